// Round 3
// baseline (688.788 us; speedup 1.0000x reference)
//
#include <hip/hip_runtime.h>
#include <math.h>

#define IMGS 16
#define EMB 2400
#define HW 196
#define CAPS 64
#define ATTK 180
#define NPOOL 15
#define NCOLS (IMGS * HW)  // 3136

typedef __attribute__((ext_vector_type(8))) short short8;
typedef __attribute__((ext_vector_type(4))) float f32x4;

__device__ inline unsigned short f2bf(float f) {
    unsigned int u = __builtin_bit_cast(unsigned int, f);
    u += 0x7fffu + ((u >> 16) & 1u);  // round-to-nearest-even
    return (unsigned short)(u >> 16);
}
__device__ inline float bf2f(unsigned int lo16) {
    return __builtin_bit_cast(float, lo16 << 16);
}

// ---------------- Weldon pooling: one 64-lane wave per (img, emb) row ----------------
// 15 iterations of wave-wide max/min extraction (handles duplicates like a sort).
__global__ __launch_bounds__(256) void weldon_kernel(const float* __restrict__ g,
                                                     float* __restrict__ hpool) {
    int wid = (blockIdx.x * 256 + threadIdx.x) >> 6;  // row = i*EMB+e
    int lane = threadIdx.x & 63;
    const float* row = g + (size_t)wid * HW;
    float v[4], w[4];
#pragma unroll
    for (int q = 0; q < 4; q++) {
        int e = lane + 64 * q;
        float x = (e < HW) ? row[e] : 0.f;
        v[q] = (e < HW) ? x : -INFINITY;
        w[q] = (e < HW) ? x : INFINITY;
    }
    float stop = 0.f, sbot = 0.f;
#pragma unroll 1
    for (int it = 0; it < NPOOL; ++it) {
        float m = fmaxf(fmaxf(v[0], v[1]), fmaxf(v[2], v[3]));
#pragma unroll
        for (int s = 32; s; s >>= 1) m = fmaxf(m, __shfl_xor(m, s, 64));
        stop += m;
        unsigned long long mask = __ballot(v[0] == m || v[1] == m || v[2] == m || v[3] == m);
        if (lane == __ffsll(mask) - 1) {
            if (v[0] == m) v[0] = -INFINITY;
            else if (v[1] == m) v[1] = -INFINITY;
            else if (v[2] == m) v[2] = -INFINITY;
            else v[3] = -INFINITY;
        }
        float n = fminf(fminf(w[0], w[1]), fminf(w[2], w[3]));
#pragma unroll
        for (int s = 32; s; s >>= 1) n = fminf(n, __shfl_xor(n, s, 64));
        sbot += n;
        unsigned long long mask2 = __ballot(w[0] == n || w[1] == n || w[2] == n || w[3] == n);
        if (lane == __ffsll(mask2) - 1) {
            if (w[0] == n) w[0] = INFINITY;
            else if (w[1] == n) w[1] = INFINITY;
            else if (w[2] == n) w[2] = INFINITY;
            else w[3] = INFINITY;
        }
    }
    if (lane == 0) hpool[wid] = stop / 15.0f + sbot / 15.0f;
}

// ---------------- x = hpool @ fc_w.T + fc_b ----------------
__global__ void x_kernel(const float* __restrict__ hpool, const float* __restrict__ fc_w,
                         const float* __restrict__ fc_b, float* __restrict__ x_out) {
    int o = blockIdx.x;
    int lane = threadIdx.x;  // 64
    float acc[IMGS];
#pragma unroll
    for (int i = 0; i < IMGS; i++) acc[i] = 0.f;
    const float* wrow = fc_w + (size_t)o * EMB;
    for (int e = lane; e < EMB; e += 64) {
        float wv = wrow[e];
#pragma unroll
        for (int i = 0; i < IMGS; i++) acc[i] += hpool[i * EMB + e] * wv;
    }
#pragma unroll
    for (int i = 0; i < IMGS; i++) {
#pragma unroll
        for (int s = 32; s > 0; s >>= 1) acc[i] += __shfl_xor(acc[i], s, 64);
    }
    if (lane == 0) {
        float bo = fc_b[o];
#pragma unroll
        for (int i = 0; i < IMGS; i++) x_out[i * EMB + o] = acc[i] + bo;
    }
}

// ---------------- top-180 per caption, rank-count, parallel over e ----------------
__global__ void topk_kernel(const float* __restrict__ caps, int* __restrict__ idxs,
                            float* __restrict__ vals) {
    __shared__ float row[EMB];
    int c = blockIdx.y;
    int tid = threadIdx.x;
    for (int e = tid; e < EMB; e += 256) row[e] = caps[(size_t)c * EMB + e];
    __syncthreads();
    int e = blockIdx.x * 256 + tid;
    if (e >= EMB) return;
    float v = row[e];
    int cnt = 0;
    for (int j = 0; j < EMB; j += 4) {
        float4 q = *(const float4*)&row[j];
        cnt += (q.x > v) || (q.x == v && (j + 0) < e);
        cnt += (q.y > v) || (q.y == v && (j + 1) < e);
        cnt += (q.z > v) || (q.z == v && (j + 2) < e);
        cnt += (q.w > v) || (q.w == v && (j + 3) < e);
    }
    if (cnt < ATTK) {
        idxs[c * ATTK + cnt] = e;
        vals[c * ATTK + cnt] = fabsf(v);
    }
}

// ---------------- fc_w fp32 -> bf16 row-major copy ----------------
__global__ void convert_w_kernel(const float* __restrict__ w, unsigned short* __restrict__ wbf) {
    int i = (blockIdx.x * 256 + threadIdx.x) * 4;
    if (i >= EMB * EMB) return;
    float4 a = *(const float4*)&w[i];
    ushort4 r;
    r.x = f2bf(a.x); r.y = f2bf(a.y); r.z = f2bf(a.z); r.w = f2bf(a.w);
    *(ushort4*)&wbf[i] = r;
}

// ---------------- gT[n][e] = bf16(g[i(n)][e][hw(n)]), n = i*196+hw ----------------
__global__ void transpose_g_kernel(const float* __restrict__ g, unsigned short* __restrict__ gT) {
    __shared__ float t[96][50];
    int i = blockIdx.z;
    int e0 = blockIdx.y * 96;
    int h0 = blockIdx.x * 49;
    int tid = threadIdx.x;
    for (int f = tid; f < 96 * 49; f += 256) {
        int e = f / 49, hh = f % 49;
        t[e][hh] = g[(size_t)i * EMB * HW + (size_t)(e0 + e) * HW + h0 + hh];
    }
    __syncthreads();
    for (int f = tid; f < 49 * 96; f += 256) {
        int hh = f / 96, e = f % 96;
        gT[(size_t)(i * HW + h0 + hh) * EMB + e0 + e] = f2bf(t[e][hh]);
    }
}

__device__ inline uint4 load8(const unsigned short* p) { return *(const uint4*)p; }
__device__ inline uint4 load8(const float* p) {
    float4 a = *(const float4*)p;
    float4 b = *(const float4*)(p + 4);
    uint4 r;
    r.x = (unsigned)f2bf(a.x) | ((unsigned)f2bf(a.y) << 16);
    r.y = (unsigned)f2bf(a.z) | ((unsigned)f2bf(a.w) << 16);
    r.z = (unsigned)f2bf(b.x) | ((unsigned)f2bf(b.y) << 16);
    r.w = (unsigned)f2bf(b.z) | ((unsigned)f2bf(b.w) << 16);
    return r;
}

// ---------------- NT bf16 MFMA GEMM: out[m][n] = sum_k A[m][k]*B[n][k] ----------------
// 4 waves in 2x2; per-wave MFxNF frags of 16x16; BM=MF*32, BN=NF*32; BK=32.
template <int MF, int NF, bool ABS_OUT, typename TA, typename TB>
__global__ __launch_bounds__(256) void mfma_gemm_nt(const TA* __restrict__ A,
                                                    const TB* __restrict__ B,
                                                    const float* __restrict__ bias,
                                                    void* __restrict__ outp,
                                                    int M, int N, int K) {
    constexpr int BM = MF * 32, BN = NF * 32;
    __shared__ unsigned short As[BM][40];
    __shared__ unsigned short Bs[BN][40];
    int m0 = blockIdx.y * BM, n0 = blockIdx.x * BN;
    int tid = threadIdx.x;
    int w = tid >> 6, lane = tid & 63;
    int wm = (w >> 1) * (MF * 16), wn = (w & 1) * (NF * 16);
    int ln = lane & 15, ks = (lane >> 4) * 8;
    f32x4 acc[MF][NF] = {};
    constexpr int nA = BM * 4, nB = BN * 4;
    for (int k0 = 0; k0 < K; k0 += 32) {
        for (int c = tid; c < nA + nB; c += 256) {
            if (c < nA) {
                int row = c >> 2, kc = c & 3;
                *(uint4*)&As[row][kc * 8] = load8(A + (size_t)(m0 + row) * K + k0 + kc * 8);
            } else {
                int cc = c - nA;
                int row = cc >> 2, kc = cc & 3;
                *(uint4*)&Bs[row][kc * 8] = load8(B + (size_t)(n0 + row) * K + k0 + kc * 8);
            }
        }
        __syncthreads();
        short8 af[MF], bfv[NF];
#pragma unroll
        for (int mf = 0; mf < MF; mf++)
            af[mf] = *(const short8*)&As[wm + mf * 16 + ln][ks];
#pragma unroll
        for (int nf = 0; nf < NF; nf++)
            bfv[nf] = *(const short8*)&Bs[wn + nf * 16 + ln][ks];
#pragma unroll
        for (int mf = 0; mf < MF; mf++)
#pragma unroll
            for (int nf = 0; nf < NF; nf++)
                acc[mf][nf] = __builtin_amdgcn_mfma_f32_16x16x32_bf16(af[mf], bfv[nf],
                                                                      acc[mf][nf], 0, 0, 0);
        __syncthreads();
    }
#pragma unroll
    for (int mf = 0; mf < MF; mf++) {
#pragma unroll
        for (int nf = 0; nf < NF; nf++) {
#pragma unroll
            for (int r = 0; r < 4; r++) {
                int row = m0 + wm + mf * 16 + (lane >> 4) * 4 + r;
                int col = n0 + wn + nf * 16 + ln;
                float v = acc[mf][nf][r];
                if (ABS_OUT) {
                    ((unsigned short*)outp)[(size_t)row * N + col] = f2bf(fabsf(v));
                } else {
                    ((float*)outp)[(size_t)row * N + col] = v + bias[col];
                }
            }
        }
    }
}

// ---------------- heat: H[c,n] = sum_j vals[c,j] * Abf[idx[c,j], n], 4 cols/thread ----------------
__global__ void heat_kernel(const int* __restrict__ idxs, const float* __restrict__ vals,
                            const unsigned short* __restrict__ A, float* __restrict__ H) {
    __shared__ int sidx[ATTK];
    __shared__ float sval[ATTK];
    int c = blockIdx.y;
    int tid = threadIdx.x;
    if (tid < ATTK) {
        sidx[tid] = idxs[c * ATTK + tid];
        sval[tid] = vals[c * ATTK + tid];
    }
    __syncthreads();
    int n = (blockIdx.x * 256 + tid) * 4;
    if (n >= NCOLS) return;
    float a0 = 0.f, a1 = 0.f, a2 = 0.f, a3 = 0.f;
    for (int j = 0; j < ATTK; j++) {
        uint2 p = *(const uint2*)&A[(size_t)sidx[j] * NCOLS + n];
        float sv = sval[j];
        a0 += sv * bf2f(p.x & 0xffffu);
        a1 += sv * bf2f(p.x >> 16);
        a2 += sv * bf2f(p.y & 0xffffu);
        a3 += sv * bf2f(p.y >> 16);
    }
    float4 r = {a0, a1, a2, a3};
    *(float4*)&H[(size_t)c * NCOLS + n] = r;
}

// ---------------- normalize per (c, i) over hw ----------------
__global__ void norm_kernel(float* __restrict__ H) {
    int c = blockIdx.x / IMGS, i = blockIdx.x % IMGS;
    float* p = H + (size_t)c * NCOLS + i * HW;
    int lane = threadIdx.x;
    float s = 0.f;
    for (int hw = lane; hw < HW; hw += 64) s += p[hw];
#pragma unroll
    for (int d = 32; d > 0; d >>= 1) s += __shfl_xor(s, d, 64);
    float inv = 1.0f / s;
    for (int hw = lane; hw < HW; hw += 64) p[hw] *= inv;
}

// ---------------- xa_pre[i, c, e] = sum_hw Hn[c, i*196+hw] * g[i, e, hw] -> bf16 ----------------
__global__ void xapre_kernel(const float* __restrict__ H, const float* __restrict__ g,
                             unsigned short* __restrict__ P) {
    __shared__ float h[8][HW];
    int i = blockIdx.z;
    int c0 = blockIdx.y * 8;
    int e0 = blockIdx.x * 1200;
    int tid = threadIdx.x;
    for (int flat = tid; flat < 8 * HW; flat += 256) {
        int cl = flat / HW, hw = flat % HW;
        h[cl][hw] = H[(size_t)(c0 + cl) * NCOLS + i * HW + hw];
    }
    __syncthreads();
    for (int l = 0; l < 5; l++) {
        int off = l * 256 + tid;
        if (off >= 1200) break;
        int e = e0 + off;
        float acc[8] = {};
        const float4* grow = (const float4*)(g + (size_t)i * EMB * HW + (size_t)e * HW);
        for (int q = 0; q < HW / 4; q++) {
            float4 g4 = grow[q];
#pragma unroll
            for (int cl = 0; cl < 8; cl++) {
                acc[cl] += h[cl][4 * q + 0] * g4.x + h[cl][4 * q + 1] * g4.y +
                           h[cl][4 * q + 2] * g4.z + h[cl][4 * q + 3] * g4.w;
            }
        }
#pragma unroll
        for (int cl = 0; cl < 8; cl++)
            P[((size_t)i * CAPS + c0 + cl) * EMB + e] = f2bf(acc[cl]);
    }
}

extern "C" void kernel_launch(void* const* d_in, const int* in_sizes, int n_in,
                              void* d_out, int out_size, void* d_ws, size_t ws_size,
                              hipStream_t stream) {
    const float* g = (const float*)d_in[0];
    const float* caps = (const float*)d_in[1];
    const float* fc_w = (const float*)d_in[2];
    const float* fc_b = (const float*)d_in[3];

    float* out = (float*)d_out;
    float* x_out = out;                    // 38400
    float* xa_out = out + 38400;           // 2457600
    float* g_out = out + 38400 + 2457600;  // 7526400 floats
    unsigned short* Abf = (unsigned short*)g_out;    // |gf| bf16 [2400][3136]
    unsigned short* gT = Abf + (size_t)EMB * NCOLS;  // bf16 [3136][2400]

    float* ws = (float*)d_ws;
    float* hpool = ws;                           // 38400
    int* idxs = (int*)(ws + 38400);              // 11520
    float* vals = ws + 49920;                    // 11520
    float* H = ws + 61440;                       // 200704
    unsigned short* Pbf = (unsigned short*)(ws + 262144);
    unsigned short* wbf = (unsigned short*)(ws + 1490944);
    bool use_wbf = ws_size >= (size_t)17483776;

    weldon_kernel<<<(IMGS * EMB) / 4, 256, 0, stream>>>(g, hpool);
    x_kernel<<<EMB, 64, 0, stream>>>(hpool, fc_w, fc_b, x_out);
    topk_kernel<<<dim3(10, CAPS), 256, 0, stream>>>(caps, idxs, vals);
    transpose_g_kernel<<<dim3(4, 25, IMGS), 256, 0, stream>>>(g, gT);

    if (use_wbf) {
        convert_w_kernel<<<(EMB * EMB / 4 + 255) / 256, 256, 0, stream>>>(fc_w, wbf);
        mfma_gemm_nt<3, 7, true, unsigned short, unsigned short>
            <<<dim3(NCOLS / 224, EMB / 96), 256, 0, stream>>>(wbf, gT, nullptr, Abf,
                                                              EMB, NCOLS, EMB);
    } else {
        mfma_gemm_nt<3, 7, true, float, unsigned short>
            <<<dim3(NCOLS / 224, EMB / 96), 256, 0, stream>>>(fc_w, gT, nullptr, Abf,
                                                              EMB, NCOLS, EMB);
    }
    heat_kernel<<<dim3((NCOLS / 4 + 255) / 256, CAPS), 256, 0, stream>>>(idxs, vals, Abf, H);
    norm_kernel<<<CAPS * IMGS, 64, 0, stream>>>(H);
    hipMemcpyAsync(g_out, g, sizeof(float) * (size_t)IMGS * EMB * HW,
                   hipMemcpyDeviceToDevice, stream);
    xapre_kernel<<<dim3(2, 8, IMGS), 256, 0, stream>>>(H, g, Pbf);
    if (use_wbf) {
        mfma_gemm_nt<4, 5, false, unsigned short, unsigned short>
            <<<dim3(EMB / 160, (IMGS * CAPS) / 128), 256, 0, stream>>>(Pbf, wbf, fc_b, xa_out,
                                                                       IMGS * CAPS, EMB, EMB);
    } else {
        mfma_gemm_nt<4, 5, false, unsigned short, float>
            <<<dim3(EMB / 160, (IMGS * CAPS) / 128), 256, 0, stream>>>(Pbf, fc_w, fc_b, xa_out,
                                                                       IMGS * CAPS, EMB, EMB);
    }
}

// Round 4
// 481.316 us; speedup vs baseline: 1.4310x; 1.4310x over previous
//
#include <hip/hip_runtime.h>
#include <math.h>

#define IMGS 16
#define EMB 2400
#define HW 196
#define CAPS 64
#define ATTK 180
#define NPOOL 15
#define NCOLS (IMGS * HW)  // 3136

typedef __attribute__((ext_vector_type(8))) short short8;
typedef __attribute__((ext_vector_type(4))) float f32x4;

__device__ inline unsigned short f2bf(float f) {
    unsigned int u = __builtin_bit_cast(unsigned int, f);
    u += 0x7fffu + ((u >> 16) & 1u);  // round-to-nearest-even
    return (unsigned short)(u >> 16);
}
__device__ inline float bf2f(unsigned int lo16) {
    return __builtin_bit_cast(float, lo16 << 16);
}

// ---------------- Weldon pooling: one 64-lane wave per (img, emb) row ----------------
__global__ __launch_bounds__(256) void weldon_kernel(const float* __restrict__ g,
                                                     float* __restrict__ hpool) {
    int wid = (blockIdx.x * 256 + threadIdx.x) >> 6;
    int lane = threadIdx.x & 63;
    const float* row = g + (size_t)wid * HW;
    float v[4], w[4];
#pragma unroll
    for (int q = 0; q < 4; q++) {
        int e = lane + 64 * q;
        float x = (e < HW) ? row[e] : 0.f;
        v[q] = (e < HW) ? x : -INFINITY;
        w[q] = (e < HW) ? x : INFINITY;
    }
    float stop = 0.f, sbot = 0.f;
#pragma unroll 1
    for (int it = 0; it < NPOOL; ++it) {
        float m = fmaxf(fmaxf(v[0], v[1]), fmaxf(v[2], v[3]));
#pragma unroll
        for (int s = 32; s; s >>= 1) m = fmaxf(m, __shfl_xor(m, s, 64));
        stop += m;
        unsigned long long mask = __ballot(v[0] == m || v[1] == m || v[2] == m || v[3] == m);
        if (lane == __ffsll(mask) - 1) {
            if (v[0] == m) v[0] = -INFINITY;
            else if (v[1] == m) v[1] = -INFINITY;
            else if (v[2] == m) v[2] = -INFINITY;
            else v[3] = -INFINITY;
        }
        float n = fminf(fminf(w[0], w[1]), fminf(w[2], w[3]));
#pragma unroll
        for (int s = 32; s; s >>= 1) n = fminf(n, __shfl_xor(n, s, 64));
        sbot += n;
        unsigned long long mask2 = __ballot(w[0] == n || w[1] == n || w[2] == n || w[3] == n);
        if (lane == __ffsll(mask2) - 1) {
            if (w[0] == n) w[0] = INFINITY;
            else if (w[1] == n) w[1] = INFINITY;
            else if (w[2] == n) w[2] = INFINITY;
            else w[3] = INFINITY;
        }
    }
    if (lane == 0) hpool[wid] = stop / 15.0f + sbot / 15.0f;
}

// ---------------- x = hpool @ fc_w.T + fc_b ----------------
__global__ void x_kernel(const float* __restrict__ hpool, const float* __restrict__ fc_w,
                         const float* __restrict__ fc_b, float* __restrict__ x_out) {
    int o = blockIdx.x;
    int lane = threadIdx.x;  // 64
    float acc[IMGS];
#pragma unroll
    for (int i = 0; i < IMGS; i++) acc[i] = 0.f;
    const float* wrow = fc_w + (size_t)o * EMB;
    for (int e = lane; e < EMB; e += 64) {
        float wv = wrow[e];
#pragma unroll
        for (int i = 0; i < IMGS; i++) acc[i] += hpool[i * EMB + e] * wv;
    }
#pragma unroll
    for (int i = 0; i < IMGS; i++) {
#pragma unroll
        for (int s = 32; s > 0; s >>= 1) acc[i] += __shfl_xor(acc[i], s, 64);
    }
    if (lane == 0) {
        float bo = fc_b[o];
#pragma unroll
        for (int i = 0; i < IMGS; i++) x_out[i * EMB + o] = acc[i] + bo;
    }
}

// ---------------- top-180 per caption, rank-count, parallel over e ----------------
__global__ void topk_kernel(const float* __restrict__ caps, int* __restrict__ idxs,
                            float* __restrict__ vals) {
    __shared__ float row[EMB];
    int c = blockIdx.y;
    int tid = threadIdx.x;
    for (int e = tid; e < EMB; e += 256) row[e] = caps[(size_t)c * EMB + e];
    __syncthreads();
    int e = blockIdx.x * 256 + tid;
    if (e >= EMB) return;
    float v = row[e];
    int cnt = 0;
    for (int j = 0; j < EMB; j += 4) {
        float4 q = *(const float4*)&row[j];
        cnt += (q.x > v) || (q.x == v && (j + 0) < e);
        cnt += (q.y > v) || (q.y == v && (j + 1) < e);
        cnt += (q.z > v) || (q.z == v && (j + 2) < e);
        cnt += (q.w > v) || (q.w == v && (j + 3) < e);
    }
    if (cnt < ATTK) {
        idxs[c * ATTK + cnt] = e;
        vals[c * ATTK + cnt] = fabsf(v);
    }
}

// ---------------- fc_w fp32 -> bf16 row-major copy ----------------
__global__ void convert_w_kernel(const float* __restrict__ w, unsigned short* __restrict__ wbf) {
    int i = (blockIdx.x * 256 + threadIdx.x) * 4;
    if (i >= EMB * EMB) return;
    float4 a = *(const float4*)&w[i];
    ushort4 r;
    r.x = f2bf(a.x); r.y = f2bf(a.y); r.z = f2bf(a.z); r.w = f2bf(a.w);
    *(ushort4*)&wbf[i] = r;
}

// ---------------- gT[n][e] = bf16(g[i(n)][e][hw(n)]) ----------------
__global__ void transpose_g_kernel(const float* __restrict__ g, unsigned short* __restrict__ gT) {
    __shared__ float t[96][50];
    int i = blockIdx.z;
    int e0 = blockIdx.y * 96;
    int h0 = blockIdx.x * 49;
    int tid = threadIdx.x;
    for (int f = tid; f < 96 * 49; f += 256) {
        int e = f / 49, hh = f % 49;
        t[e][hh] = g[(size_t)i * EMB * HW + (size_t)(e0 + e) * HW + h0 + hh];
    }
    __syncthreads();
    for (int f = tid; f < 49 * 96; f += 256) {
        int hh = f / 96, e = f % 96;
        gT[(size_t)(i * HW + h0 + hh) * EMB + e0 + e] = f2bf(t[e][hh]);
    }
}

__device__ inline uint4 load8(const unsigned short* p) { return *(const uint4*)p; }
__device__ inline uint4 load8(const float* p) {
    float4 a = *(const float4*)p;
    float4 b = *(const float4*)(p + 4);
    uint4 r;
    r.x = (unsigned)f2bf(a.x) | ((unsigned)f2bf(a.y) << 16);
    r.y = (unsigned)f2bf(a.z) | ((unsigned)f2bf(a.w) << 16);
    r.z = (unsigned)f2bf(b.x) | ((unsigned)f2bf(b.y) << 16);
    r.w = (unsigned)f2bf(b.z) | ((unsigned)f2bf(b.w) << 16);
    return r;
}

// ---------------- NT bf16 MFMA GEMM with register-prefetch pipeline ----------------
// 4 waves 2x2; per-wave MFxNF 16x16 frags; BM=MF*32, BN=NF*32; BK=32.
// OUT_MODE: 0 = bf16 |v|; 1 = f32 v+bias; 2 = f32 partial at outp + z*M*N (split-K)
template <int MF, int NF, int OUT_MODE, typename TA, typename TB>
__global__ __launch_bounds__(256) void mfma_gemm_nt(const TA* __restrict__ A,
                                                    const TB* __restrict__ B,
                                                    const float* __restrict__ bias,
                                                    void* __restrict__ outp,
                                                    int M, int N, int K, int kper) {
    constexpr int BM = MF * 32, BN = NF * 32;
    constexpr int nA = BM * 4, nTot = (BM + BN) * 4;
    constexpr int NCH = (nTot + 255) / 256;
    __shared__ unsigned short As[BM][40];
    __shared__ unsigned short Bs[BN][40];
    int m0 = blockIdx.y * BM, n0 = blockIdx.x * BN;
    int sk = blockIdx.z;
    int kb = sk * kper, ke = kb + kper;
    int tid = threadIdx.x;
    int w = tid >> 6, lane = tid & 63;
    int wm = (w >> 1) * (MF * 16), wn = (w & 1) * (NF * 16);
    int ln = lane & 15, ks = (lane >> 4) * 8;

    uint4 r[NCH];
#pragma unroll
    for (int j = 0; j < NCH; j++) {
        int c = tid + 256 * j;
        if (c < nTot) {
            if (c < nA) {
                int row = c >> 2, kc = c & 3;
                r[j] = load8(A + (size_t)(m0 + row) * K + kb + kc * 8);
            } else {
                int cc = c - nA, row = cc >> 2, kc = cc & 3;
                r[j] = load8(B + (size_t)(n0 + row) * K + kb + kc * 8);
            }
        }
    }

    f32x4 acc[MF][NF] = {};
    for (int k0 = kb; k0 < ke; k0 += 32) {
#pragma unroll
        for (int j = 0; j < NCH; j++) {
            int c = tid + 256 * j;
            if (c < nTot) {
                if (c < nA) {
                    int row = c >> 2, kc = c & 3;
                    *(uint4*)&As[row][kc * 8] = r[j];
                } else {
                    int cc = c - nA, row = cc >> 2, kc = cc & 3;
                    *(uint4*)&Bs[row][kc * 8] = r[j];
                }
            }
        }
        __syncthreads();
        if (k0 + 32 < ke) {
#pragma unroll
            for (int j = 0; j < NCH; j++) {
                int c = tid + 256 * j;
                if (c < nTot) {
                    if (c < nA) {
                        int row = c >> 2, kc = c & 3;
                        r[j] = load8(A + (size_t)(m0 + row) * K + (k0 + 32) + kc * 8);
                    } else {
                        int cc = c - nA, row = cc >> 2, kc = cc & 3;
                        r[j] = load8(B + (size_t)(n0 + row) * K + (k0 + 32) + kc * 8);
                    }
                }
            }
        }
        short8 af[MF], bfv[NF];
#pragma unroll
        for (int mf = 0; mf < MF; mf++)
            af[mf] = *(const short8*)&As[wm + mf * 16 + ln][ks];
#pragma unroll
        for (int nf = 0; nf < NF; nf++)
            bfv[nf] = *(const short8*)&Bs[wn + nf * 16 + ln][ks];
#pragma unroll
        for (int mf = 0; mf < MF; mf++)
#pragma unroll
            for (int nf = 0; nf < NF; nf++)
                acc[mf][nf] = __builtin_amdgcn_mfma_f32_16x16x32_bf16(af[mf], bfv[nf],
                                                                      acc[mf][nf], 0, 0, 0);
        __syncthreads();
    }
#pragma unroll
    for (int mf = 0; mf < MF; mf++) {
#pragma unroll
        for (int nf = 0; nf < NF; nf++) {
#pragma unroll
            for (int rr = 0; rr < 4; rr++) {
                int row = m0 + wm + mf * 16 + (lane >> 4) * 4 + rr;
                int col = n0 + wn + nf * 16 + ln;
                float v = acc[mf][nf][rr];
                if (OUT_MODE == 0) {
                    ((unsigned short*)outp)[(size_t)row * N + col] = f2bf(fabsf(v));
                } else if (OUT_MODE == 1) {
                    ((float*)outp)[(size_t)row * N + col] = v + bias[col];
                } else {
                    ((float*)outp)[(size_t)sk * M * N + (size_t)row * N + col] = v;
                }
            }
        }
    }
}

// ---------------- reduce 3 split-K partials + bias -> xa_out ----------------
__global__ void reduce3_kernel(const float* __restrict__ p, const float* __restrict__ bias,
                               float* __restrict__ out) {
    int i = (blockIdx.x * 256 + threadIdx.x) * 4;
    if (i >= IMGS * CAPS * EMB) return;
    float4 a = *(const float4*)&p[i];
    float4 b = *(const float4*)&p[i + IMGS * CAPS * EMB];
    float4 c = *(const float4*)&p[i + 2 * IMGS * CAPS * EMB];
    float4 bb = *(const float4*)&bias[i % EMB];
    float4 r = {a.x + b.x + c.x + bb.x, a.y + b.y + c.y + bb.y,
                a.z + b.z + c.z + bb.z, a.w + b.w + c.w + bb.w};
    *(float4*)&out[i] = r;
}

// ---------------- heat: H[c,n] = sum_j vals[c,j] * Abf[idx[c,j], n] ----------------
__global__ void heat_kernel(const int* __restrict__ idxs, const float* __restrict__ vals,
                            const unsigned short* __restrict__ A, float* __restrict__ H) {
    __shared__ int sidx[ATTK];
    __shared__ float sval[ATTK];
    int c = blockIdx.y;
    int tid = threadIdx.x;
    if (tid < ATTK) {
        sidx[tid] = idxs[c * ATTK + tid];
        sval[tid] = vals[c * ATTK + tid];
    }
    __syncthreads();
    int n = (blockIdx.x * 256 + tid) * 4;
    if (n >= NCOLS) return;
    float a0 = 0.f, a1 = 0.f, a2 = 0.f, a3 = 0.f;
    for (int j = 0; j < ATTK; j++) {
        uint2 p = *(const uint2*)&A[(size_t)sidx[j] * NCOLS + n];
        float sv = sval[j];
        a0 += sv * bf2f(p.x & 0xffffu);
        a1 += sv * bf2f(p.x >> 16);
        a2 += sv * bf2f(p.y & 0xffffu);
        a3 += sv * bf2f(p.y >> 16);
    }
    float4 r = {a0, a1, a2, a3};
    *(float4*)&H[(size_t)c * NCOLS + n] = r;
}

// ---------------- normalize per (c, i) over hw ----------------
__global__ void norm_kernel(float* __restrict__ H) {
    int c = blockIdx.x / IMGS, i = blockIdx.x % IMGS;
    float* p = H + (size_t)c * NCOLS + i * HW;
    int lane = threadIdx.x;
    float s = 0.f;
    for (int hw = lane; hw < HW; hw += 64) s += p[hw];
#pragma unroll
    for (int d = 32; d > 0; d >>= 1) s += __shfl_xor(s, d, 64);
    float inv = 1.0f / s;
    for (int hw = lane; hw < HW; hw += 64) p[hw] *= inv;
}

// ---------------- xa_pre[i, c, e] -> bf16 ----------------
__global__ void xapre_kernel(const float* __restrict__ H, const float* __restrict__ g,
                             unsigned short* __restrict__ P) {
    __shared__ float h[8][HW];
    int i = blockIdx.z;
    int c0 = blockIdx.y * 8;
    int e0 = blockIdx.x * 1200;
    int tid = threadIdx.x;
    for (int flat = tid; flat < 8 * HW; flat += 256) {
        int cl = flat / HW, hw = flat % HW;
        h[cl][hw] = H[(size_t)(c0 + cl) * NCOLS + i * HW + hw];
    }
    __syncthreads();
    for (int l = 0; l < 5; l++) {
        int off = l * 256 + tid;
        if (off >= 1200) break;
        int e = e0 + off;
        float acc[8] = {};
        const float4* grow = (const float4*)(g + (size_t)i * EMB * HW + (size_t)e * HW);
        for (int q = 0; q < HW / 4; q++) {
            float4 g4 = grow[q];
#pragma unroll
            for (int cl = 0; cl < 8; cl++) {
                acc[cl] += h[cl][4 * q + 0] * g4.x + h[cl][4 * q + 1] * g4.y +
                           h[cl][4 * q + 2] * g4.z + h[cl][4 * q + 3] * g4.w;
            }
        }
#pragma unroll
        for (int cl = 0; cl < 8; cl++)
            P[((size_t)i * CAPS + c0 + cl) * EMB + e] = f2bf(acc[cl]);
    }
}

extern "C" void kernel_launch(void* const* d_in, const int* in_sizes, int n_in,
                              void* d_out, int out_size, void* d_ws, size_t ws_size,
                              hipStream_t stream) {
    const float* g = (const float*)d_in[0];
    const float* caps = (const float*)d_in[1];
    const float* fc_w = (const float*)d_in[2];
    const float* fc_b = (const float*)d_in[3];

    float* out = (float*)d_out;
    float* x_out = out;                    // 38400
    float* xa_out = out + 38400;           // 2457600
    float* g_out = out + 38400 + 2457600;  // 7526400 floats (30.1 MB scratch until final copy)
    unsigned short* Abf = (unsigned short*)g_out;    // |gf| bf16 [2400][3136]
    unsigned short* gT = Abf + (size_t)EMB * NCOLS;  // bf16 [3136][2400]
    float* Ppart = g_out;                            // split-K partials [3][1024][2400] f32

    float* ws = (float*)d_ws;
    float* hpool = ws;                           // 38400
    int* idxs = (int*)(ws + 38400);              // 11520
    float* vals = ws + 49920;                    // 11520
    float* H = ws + 61440;                       // 200704
    unsigned short* Pbf = (unsigned short*)(ws + 262144);
    unsigned short* wbf = (unsigned short*)(ws + 1490944);
    bool use_wbf = ws_size >= (size_t)17483776;

    weldon_kernel<<<(IMGS * EMB) / 4, 256, 0, stream>>>(g, hpool);
    x_kernel<<<EMB, 64, 0, stream>>>(hpool, fc_w, fc_b, x_out);
    topk_kernel<<<dim3(10, CAPS), 256, 0, stream>>>(caps, idxs, vals);
    transpose_g_kernel<<<dim3(4, 25, IMGS), 256, 0, stream>>>(g, gT);

    if (use_wbf) {
        convert_w_kernel<<<(EMB * EMB / 4 + 255) / 256, 256, 0, stream>>>(fc_w, wbf);
        mfma_gemm_nt<5, 2, 0, unsigned short, unsigned short>
            <<<dim3(NCOLS / 64, EMB / 160), 256, 0, stream>>>(wbf, gT, nullptr, Abf,
                                                              EMB, NCOLS, EMB, EMB);
    } else {
        mfma_gemm_nt<5, 2, 0, float, unsigned short>
            <<<dim3(NCOLS / 64, EMB / 160), 256, 0, stream>>>(fc_w, gT, nullptr, Abf,
                                                              EMB, NCOLS, EMB, EMB);
    }
    heat_kernel<<<dim3((NCOLS / 4 + 255) / 256, CAPS), 256, 0, stream>>>(idxs, vals, Abf, H);
    norm_kernel<<<CAPS * IMGS, 64, 0, stream>>>(H);
    xapre_kernel<<<dim3(2, 8, IMGS), 256, 0, stream>>>(H, g, Pbf);
    // split-K gemm3: partials into g_out scratch (Abf/gT dead), then reduce
    if (use_wbf) {
        mfma_gemm_nt<2, 3, 2, unsigned short, unsigned short>
            <<<dim3(EMB / 96, (IMGS * CAPS) / 64, 3), 256, 0, stream>>>(Pbf, wbf, nullptr, Ppart,
                                                                        IMGS * CAPS, EMB, EMB, 800);
    } else {
        mfma_gemm_nt<2, 3, 2, unsigned short, float>
            <<<dim3(EMB / 96, (IMGS * CAPS) / 64, 3), 256, 0, stream>>>(Pbf, fc_w, nullptr, Ppart,
                                                                        IMGS * CAPS, EMB, EMB, 800);
    }
    reduce3_kernel<<<(IMGS * CAPS * EMB / 4) / 256, 256, 0, stream>>>(Ppart, fc_b, xa_out);
    // g passthrough last (overwrites all g_out scratch)
    hipMemcpyAsync(g_out, g, sizeof(float) * (size_t)IMGS * EMB * HW,
                   hipMemcpyDeviceToDevice, stream);
}

// Round 5
// 356.597 us; speedup vs baseline: 1.9316x; 1.3497x over previous
//
#include <hip/hip_runtime.h>
#include <math.h>

#define IMGS 16
#define EMB 2400
#define HW 196
#define CAPS 64
#define ATTK 180
#define NPOOL 15
#define NCOLS (IMGS * HW)  // 3136
#define KPAD 224           // 196 padded to multiple of 32

typedef __attribute__((ext_vector_type(8))) short short8;
typedef __attribute__((ext_vector_type(4))) float f32x4;
typedef const __attribute__((address_space(1))) unsigned int* gas1_t;
typedef __attribute__((address_space(3))) unsigned int* las3_t;

__device__ inline unsigned short f2bf(float f) {
    unsigned int u = __builtin_bit_cast(unsigned int, f);
    u += 0x7fffu + ((u >> 16) & 1u);  // round-to-nearest-even
    return (unsigned short)(u >> 16);
}
__device__ inline float bf2f(unsigned int lo16) {
    return __builtin_bit_cast(float, lo16 << 16);
}

// ---------------- Weldon pooling: one 64-lane wave per (img, emb) row ----------------
__global__ __launch_bounds__(256) void weldon_kernel(const float* __restrict__ g,
                                                     float* __restrict__ hpool) {
    int wid = (blockIdx.x * 256 + threadIdx.x) >> 6;
    int lane = threadIdx.x & 63;
    const float* row = g + (size_t)wid * HW;
    float v[4], w[4];
#pragma unroll
    for (int q = 0; q < 4; q++) {
        int e = lane + 64 * q;
        float x = (e < HW) ? row[e] : 0.f;
        v[q] = (e < HW) ? x : -INFINITY;
        w[q] = (e < HW) ? x : INFINITY;
    }
    float stop = 0.f, sbot = 0.f;
#pragma unroll 1
    for (int it = 0; it < NPOOL; ++it) {
        float m = fmaxf(fmaxf(v[0], v[1]), fmaxf(v[2], v[3]));
#pragma unroll
        for (int s = 32; s; s >>= 1) m = fmaxf(m, __shfl_xor(m, s, 64));
        stop += m;
        unsigned long long mask = __ballot(v[0] == m || v[1] == m || v[2] == m || v[3] == m);
        if (lane == __ffsll(mask) - 1) {
            if (v[0] == m) v[0] = -INFINITY;
            else if (v[1] == m) v[1] = -INFINITY;
            else if (v[2] == m) v[2] = -INFINITY;
            else v[3] = -INFINITY;
        }
        float n = fminf(fminf(w[0], w[1]), fminf(w[2], w[3]));
#pragma unroll
        for (int s = 32; s; s >>= 1) n = fminf(n, __shfl_xor(n, s, 64));
        sbot += n;
        unsigned long long mask2 = __ballot(w[0] == n || w[1] == n || w[2] == n || w[3] == n);
        if (lane == __ffsll(mask2) - 1) {
            if (w[0] == n) w[0] = INFINITY;
            else if (w[1] == n) w[1] = INFINITY;
            else if (w[2] == n) w[2] = INFINITY;
            else w[3] = INFINITY;
        }
    }
    if (lane == 0) hpool[wid] = stop / 15.0f + sbot / 15.0f;
}

// ---------------- x = hpool @ fc_w.T + fc_b ----------------
__global__ void x_kernel(const float* __restrict__ hpool, const float* __restrict__ fc_w,
                         const float* __restrict__ fc_b, float* __restrict__ x_out) {
    int o = blockIdx.x;
    int lane = threadIdx.x;  // 64
    float acc[IMGS];
#pragma unroll
    for (int i = 0; i < IMGS; i++) acc[i] = 0.f;
    const float* wrow = fc_w + (size_t)o * EMB;
    for (int e = lane; e < EMB; e += 64) {
        float wv = wrow[e];
#pragma unroll
        for (int i = 0; i < IMGS; i++) acc[i] += hpool[i * EMB + e] * wv;
    }
#pragma unroll
    for (int i = 0; i < IMGS; i++) {
#pragma unroll
        for (int s = 32; s > 0; s >>= 1) acc[i] += __shfl_xor(acc[i], s, 64);
    }
    if (lane == 0) {
        float bo = fc_b[o];
#pragma unroll
        for (int i = 0; i < IMGS; i++) x_out[i * EMB + o] = acc[i] + bo;
    }
}

// ---------------- top-180 per caption, rank-count, parallel over e ----------------
__global__ void topk_kernel(const float* __restrict__ caps, int* __restrict__ idxs,
                            float* __restrict__ vals) {
    __shared__ float row[EMB];
    int c = blockIdx.y;
    int tid = threadIdx.x;
    for (int e = tid; e < EMB; e += 256) row[e] = caps[(size_t)c * EMB + e];
    __syncthreads();
    int e = blockIdx.x * 256 + tid;
    if (e >= EMB) return;
    float v = row[e];
    int cnt = 0;
    for (int j = 0; j < EMB; j += 4) {
        float4 q = *(const float4*)&row[j];
        cnt += (q.x > v) || (q.x == v && (j + 0) < e);
        cnt += (q.y > v) || (q.y == v && (j + 1) < e);
        cnt += (q.z > v) || (q.z == v && (j + 2) < e);
        cnt += (q.w > v) || (q.w == v && (j + 3) < e);
    }
    if (cnt < ATTK) {
        idxs[c * ATTK + cnt] = e;
        vals[c * ATTK + cnt] = fabsf(v);
    }
}

// ---------------- fc_w fp32 -> bf16 row-major copy ----------------
__global__ void convert_w_kernel(const float* __restrict__ w, unsigned short* __restrict__ wbf) {
    int i = (blockIdx.x * 256 + threadIdx.x) * 4;
    if (i >= EMB * EMB) return;
    float4 a = *(const float4*)&w[i];
    ushort4 r;
    r.x = f2bf(a.x); r.y = f2bf(a.y); r.z = f2bf(a.z); r.w = f2bf(a.w);
    *(ushort4*)&wbf[i] = r;
}

// ---------------- gbf[i][e][KPAD] = bf16(g[i][e][hw]), zero-padded ----------------
// one wave per (i,e) row; 4 waves/block
__global__ __launch_bounds__(256) void convert_g_kernel(const float* __restrict__ g,
                                                        unsigned short* __restrict__ gbf) {
    int row = blockIdx.x * 4 + (threadIdx.x >> 6);
    int l = threadIdx.x & 63;
    const float* src = g + (size_t)row * HW;
    unsigned short* dst = gbf + (size_t)row * KPAD;
    if (l < KPAD / 4) {
        ushort4 o = {0, 0, 0, 0};
        if (l < HW / 4) {  // 196/4 = 49 exact
            float4 v = ((const float4*)src)[l];
            o.x = f2bf(v.x); o.y = f2bf(v.y); o.z = f2bf(v.z); o.w = f2bf(v.w);
        }
        ((ushort4*)dst)[l] = o;
    }
}

// ---------------- gT[n][e] = bf16(g[i(n)][e][hw(n)]) ----------------
__global__ void transpose_g_kernel(const float* __restrict__ g, unsigned short* __restrict__ gT) {
    __shared__ float t[96][50];
    int i = blockIdx.z;
    int e0 = blockIdx.y * 96;
    int h0 = blockIdx.x * 49;
    int tid = threadIdx.x;
    for (int f = tid; f < 96 * 49; f += 256) {
        int e = f / 49, hh = f % 49;
        t[e][hh] = g[(size_t)i * EMB * HW + (size_t)(e0 + e) * HW + h0 + hh];
    }
    __syncthreads();
    for (int f = tid; f < 49 * 96; f += 256) {
        int hh = f / 96, e = f % 96;
        gT[(size_t)(i * HW + h0 + hh) * EMB + e0 + e] = f2bf(t[e][hh]);
    }
}

// ======== NT bf16 MFMA GEMM, global_load_lds staging, double-buffered 1-barrier loop ========
// 4 waves 2x2; per-wave MFxNF 16x16 frags; BM=MF*32, BN=NF*32; BK=32.
// OUT_MODE: 0 = bf16 |v|; 2 = f32 partial at out+z*M*N; 3 = bf16 at out+z*M*N.
// az/bz: element stride added to A/B per blockIdx.z (batched mode). If az==bz==0,
// z is a split-K index: kb = z*kper.
template <int MF, int NF, int OUT_MODE>
__global__ __launch_bounds__(256) void gemm_gll(const unsigned short* __restrict__ A,
                                                const unsigned short* __restrict__ B,
                                                void* __restrict__ outp,
                                                int M, int N, int K, int kper,
                                                long az, long bz) {
    constexpr int BM = MF * 32, BN = NF * 32;
    constexpr int ROWS = BM + BN;       // LDS rows (64B each) per buffer
    constexpr int NCALL = ROWS / 16;    // 1KB global_load_lds calls per buffer
    __shared__ unsigned short lds[2][ROWS][32];
    int m0 = blockIdx.y * BM, n0 = blockIdx.x * BN;
    int z = blockIdx.z;
    const unsigned short* Ab = A + (size_t)z * az;
    const unsigned short* Bb = B + (size_t)z * bz;
    int kb = (az == 0 && bz == 0) ? z * kper : 0;
    int nt = kper / 32;
    int tid = threadIdx.x, w = tid >> 6, lane = tid & 63;
    int wm = (w >> 1) * (MF * 16), wn = (w & 1) * (NF * 16);
    int ln = lane & 15, ks = (lane >> 4) * 8;
    int srow = lane >> 2;          // row within 16-row group
    int skc = (lane & 3) * 8;      // k-element offset within row

    auto STAGE = [&](int buf, int t) {
        int k0 = kb + t * 32;
        for (int j = w; j < NCALL; j += 4) {
            int r = j * 16 + srow;
            const unsigned short* src = (r < BM)
                ? (Ab + (size_t)(m0 + r) * K + k0 + skc)
                : (Bb + (size_t)(n0 + r - BM) * K + k0 + skc);
            __builtin_amdgcn_global_load_lds((gas1_t)(const void*)src,
                                             (las3_t)(void*)&lds[buf][j * 16][0], 16, 0, 0);
        }
    };

    STAGE(0, 0);
    __syncthreads();  // drains vmcnt before first read
    f32x4 acc[MF][NF] = {};
    int cur = 0;
    for (int t = 0; t < nt; ++t) {
        if (t + 1 < nt) STAGE(cur ^ 1, t + 1);  // loads in flight during ds_read+MFMA
        short8 af[MF], bfv[NF];
#pragma unroll
        for (int mf = 0; mf < MF; mf++)
            af[mf] = *(const short8*)&lds[cur][wm + mf * 16 + ln][ks];
#pragma unroll
        for (int nf = 0; nf < NF; nf++)
            bfv[nf] = *(const short8*)&lds[cur][BM + wn + nf * 16 + ln][ks];
#pragma unroll
        for (int mf = 0; mf < MF; mf++)
#pragma unroll
            for (int nf = 0; nf < NF; nf++)
                acc[mf][nf] = __builtin_amdgcn_mfma_f32_16x16x32_bf16(af[mf], bfv[nf],
                                                                      acc[mf][nf], 0, 0, 0);
        __syncthreads();  // vmcnt(0)+barrier: staged tile ready, reads of cur done
        cur ^= 1;
    }
#pragma unroll
    for (int mf = 0; mf < MF; mf++) {
#pragma unroll
        for (int nf = 0; nf < NF; nf++) {
#pragma unroll
            for (int rr = 0; rr < 4; rr++) {
                int row = m0 + wm + mf * 16 + (lane >> 4) * 4 + rr;
                int col = n0 + wn + nf * 16 + ln;
                float v = acc[mf][nf][rr];
                if (OUT_MODE == 0) {
                    ((unsigned short*)outp)[(size_t)row * N + col] = f2bf(fabsf(v));
                } else if (OUT_MODE == 2) {
                    ((float*)outp)[(size_t)z * M * N + (size_t)row * N + col] = v;
                } else {
                    ((unsigned short*)outp)[(size_t)z * M * N + (size_t)row * N + col] = f2bf(v);
                }
            }
        }
    }
}

// ======== fallback reg-staged NT GEMM (used only if ws too small for wbf) ========
__device__ inline uint4 load8(const unsigned short* p) { return *(const uint4*)p; }
__device__ inline uint4 load8(const float* p) {
    float4 a = *(const float4*)p;
    float4 b = *(const float4*)(p + 4);
    uint4 r;
    r.x = (unsigned)f2bf(a.x) | ((unsigned)f2bf(a.y) << 16);
    r.y = (unsigned)f2bf(a.z) | ((unsigned)f2bf(a.w) << 16);
    r.z = (unsigned)f2bf(b.x) | ((unsigned)f2bf(b.y) << 16);
    r.w = (unsigned)f2bf(b.z) | ((unsigned)f2bf(b.w) << 16);
    return r;
}

template <int MF, int NF, int OUT_MODE, typename TA, typename TB>
__global__ __launch_bounds__(256) void mfma_gemm_nt(const TA* __restrict__ A,
                                                    const TB* __restrict__ B,
                                                    const float* __restrict__ bias,
                                                    void* __restrict__ outp,
                                                    int M, int N, int K, int kper) {
    constexpr int BM = MF * 32, BN = NF * 32;
    constexpr int nA = BM * 4, nTot = (BM + BN) * 4;
    constexpr int NCH = (nTot + 255) / 256;
    __shared__ unsigned short As[BM][40];
    __shared__ unsigned short Bs[BN][40];
    int m0 = blockIdx.y * BM, n0 = blockIdx.x * BN;
    int sk = blockIdx.z;
    int kb = sk * kper, ke = kb + kper;
    int tid = threadIdx.x;
    int w = tid >> 6, lane = tid & 63;
    int wm = (w >> 1) * (MF * 16), wn = (w & 1) * (NF * 16);
    int ln = lane & 15, ks = (lane >> 4) * 8;
    uint4 r[NCH];
#pragma unroll
    for (int j = 0; j < NCH; j++) {
        int c = tid + 256 * j;
        if (c < nTot) {
            if (c < nA) {
                int row = c >> 2, kc = c & 3;
                r[j] = load8(A + (size_t)(m0 + row) * K + kb + kc * 8);
            } else {
                int cc = c - nA, row = cc >> 2, kc = cc & 3;
                r[j] = load8(B + (size_t)(n0 + row) * K + kb + kc * 8);
            }
        }
    }
    f32x4 acc[MF][NF] = {};
    for (int k0 = kb; k0 < ke; k0 += 32) {
#pragma unroll
        for (int j = 0; j < NCH; j++) {
            int c = tid + 256 * j;
            if (c < nTot) {
                if (c < nA) {
                    int row = c >> 2, kc = c & 3;
                    *(uint4*)&As[row][kc * 8] = r[j];
                } else {
                    int cc = c - nA, row = cc >> 2, kc = cc & 3;
                    *(uint4*)&Bs[row][kc * 8] = r[j];
                }
            }
        }
        __syncthreads();
        if (k0 + 32 < ke) {
#pragma unroll
            for (int j = 0; j < NCH; j++) {
                int c = tid + 256 * j;
                if (c < nTot) {
                    if (c < nA) {
                        int row = c >> 2, kc = c & 3;
                        r[j] = load8(A + (size_t)(m0 + row) * K + (k0 + 32) + kc * 8);
                    } else {
                        int cc = c - nA, row = cc >> 2, kc = cc & 3;
                        r[j] = load8(B + (size_t)(n0 + row) * K + (k0 + 32) + kc * 8);
                    }
                }
            }
        }
        short8 af[MF], bfv[NF];
#pragma unroll
        for (int mf = 0; mf < MF; mf++)
            af[mf] = *(const short8*)&As[wm + mf * 16 + ln][ks];
#pragma unroll
        for (int nf = 0; nf < NF; nf++)
            bfv[nf] = *(const short8*)&Bs[wn + nf * 16 + ln][ks];
#pragma unroll
        for (int mf = 0; mf < MF; mf++)
#pragma unroll
            for (int nf = 0; nf < NF; nf++)
                acc[mf][nf] = __builtin_amdgcn_mfma_f32_16x16x32_bf16(af[mf], bfv[nf],
                                                                      acc[mf][nf], 0, 0, 0);
        __syncthreads();
    }
#pragma unroll
    for (int mf = 0; mf < MF; mf++) {
#pragma unroll
        for (int nf = 0; nf < NF; nf++) {
#pragma unroll
            for (int rr = 0; rr < 4; rr++) {
                int row = m0 + wm + mf * 16 + (lane >> 4) * 4 + rr;
                int col = n0 + wn + nf * 16 + ln;
                float v = acc[mf][nf][rr];
                if (OUT_MODE == 0) {
                    ((unsigned short*)outp)[(size_t)row * N + col] = f2bf(fabsf(v));
                } else if (OUT_MODE == 2) {
                    ((float*)outp)[(size_t)sk * M * N + (size_t)row * N + col] = v;
                }
            }
        }
    }
}

// ---------------- reduce 3 split-K partials + bias -> xa_out ----------------
__global__ void reduce3_kernel(const float* __restrict__ p, const float* __restrict__ bias,
                               float* __restrict__ out) {
    int i = (blockIdx.x * 256 + threadIdx.x) * 4;
    if (i >= IMGS * CAPS * EMB) return;
    float4 a = *(const float4*)&p[i];
    float4 b = *(const float4*)&p[i + IMGS * CAPS * EMB];
    float4 c = *(const float4*)&p[i + 2 * IMGS * CAPS * EMB];
    float4 bb = *(const float4*)&bias[i % EMB];
    float4 r = {a.x + b.x + c.x + bb.x, a.y + b.y + c.y + bb.y,
                a.z + b.z + c.z + bb.z, a.w + b.w + c.w + bb.w};
    *(float4*)&out[i] = r;
}

// ---------------- heat: H[c,n] = sum_j vals[c,j] * Abf[idx[c,j], n] ----------------
__global__ void heat_kernel(const int* __restrict__ idxs, const float* __restrict__ vals,
                            const unsigned short* __restrict__ A, float* __restrict__ H) {
    __shared__ int sidx[ATTK];
    __shared__ float sval[ATTK];
    int c = blockIdx.y;
    int tid = threadIdx.x;
    if (tid < ATTK) {
        sidx[tid] = idxs[c * ATTK + tid];
        sval[tid] = vals[c * ATTK + tid];
    }
    __syncthreads();
    int n = (blockIdx.x * 256 + tid) * 4;
    if (n >= NCOLS) return;
    float a0 = 0.f, a1 = 0.f, a2 = 0.f, a3 = 0.f;
    for (int j = 0; j < ATTK; j++) {
        uint2 p = *(const uint2*)&A[(size_t)sidx[j] * NCOLS + n];
        float sv = sval[j];
        a0 += sv * bf2f(p.x & 0xffffu);
        a1 += sv * bf2f(p.x >> 16);
        a2 += sv * bf2f(p.y & 0xffffu);
        a3 += sv * bf2f(p.y >> 16);
    }
    float4 r = {a0, a1, a2, a3};
    *(float4*)&H[(size_t)c * NCOLS + n] = r;
}

// ---------------- norm: Hbf[i][c][KPAD] = bf16(H[c, i*196+hw] / rowsum), zero-padded ----------------
__global__ void norm_kernel(const float* __restrict__ H, unsigned short* __restrict__ Hbf) {
    int c = blockIdx.x / IMGS, i = blockIdx.x % IMGS;
    const float* p = H + (size_t)c * NCOLS + i * HW;
    int lane = threadIdx.x;  // 64
    float s = 0.f;
    for (int hw = lane; hw < HW; hw += 64) s += p[hw];
#pragma unroll
    for (int d = 32; d > 0; d >>= 1) s += __shfl_xor(s, d, 64);
    float inv = 1.0f / s;
    unsigned short* dst = Hbf + ((size_t)i * CAPS + c) * KPAD;
    for (int hw = lane; hw < KPAD; hw += 64)
        dst[hw] = (hw < HW) ? f2bf(p[hw] * inv) : (unsigned short)0;
}

extern "C" void kernel_launch(void* const* d_in, const int* in_sizes, int n_in,
                              void* d_out, int out_size, void* d_ws, size_t ws_size,
                              hipStream_t stream) {
    const float* g = (const float*)d_in[0];
    const float* caps = (const float*)d_in[1];
    const float* fc_w = (const float*)d_in[2];
    const float* fc_b = (const float*)d_in[3];

    float* out = (float*)d_out;
    float* x_out = out;                    // 38400
    float* xa_out = out + 38400;           // 2457600
    float* g_out = out + 38400 + 2457600;  // 7526400 floats = 30.1 MB scratch until final copy
    // phase 1 layout of g_out: [Abf 15.05 MB][gT 15.05 MB]
    unsigned short* Abf = (unsigned short*)g_out;
    unsigned short* gT = Abf + (size_t)EMB * NCOLS;
    // phase 2 (after heat): [gbf 17.2 MB][Hbf 0.46 MB]
    unsigned short* gbf = (unsigned short*)g_out;
    unsigned short* Hbf = gbf + (size_t)IMGS * EMB * KPAD;
    // phase 3 (after xapre): split-K partials [3][1024][2400] f32 = 29.5 MB
    float* Ppart = g_out;

    float* ws = (float*)d_ws;
    float* hpool = ws;                                      // 38400 f
    int* idxs = (int*)(ws + 38400);                         // 11520
    float* vals = ws + 49920;                               // 11520
    float* H = ws + 61440;                                  // 200704 f
    unsigned short* Pbf = (unsigned short*)(ws + 262144);   // 2457600 us, ends byte 5963776
    unsigned short* wbf = (unsigned short*)(ws + 1490944);  // 5760000 us, ends byte 17483776
    bool use_wbf = ws_size >= (size_t)17483776;

    weldon_kernel<<<(IMGS * EMB) / 4, 256, 0, stream>>>(g, hpool);
    x_kernel<<<EMB, 64, 0, stream>>>(hpool, fc_w, fc_b, x_out);
    topk_kernel<<<dim3(10, CAPS), 256, 0, stream>>>(caps, idxs, vals);
    transpose_g_kernel<<<dim3(4, 25, IMGS), 256, 0, stream>>>(g, gT);

    // ---- gemm1: Abf = |wbf @ gT^T| ----
    if (use_wbf) {
        convert_w_kernel<<<(EMB * EMB / 4 + 255) / 256, 256, 0, stream>>>(fc_w, wbf);
        gemm_gll<5, 2, 0><<<dim3(NCOLS / 64, EMB / 160, 1), 256, 0, stream>>>(
            wbf, gT, Abf, EMB, NCOLS, EMB, EMB, 0, 0);
    } else {
        mfma_gemm_nt<5, 2, 0, float, unsigned short>
            <<<dim3(NCOLS / 64, EMB / 160), 256, 0, stream>>>(fc_w, gT, nullptr, Abf,
                                                              EMB, NCOLS, EMB, EMB);
    }
    heat_kernel<<<dim3((NCOLS / 4 + 255) / 256, CAPS), 256, 0, stream>>>(idxs, vals, Abf, H);
    // ---- Abf/gT dead: build Hbf + gbf in g_out ----
    norm_kernel<<<CAPS * IMGS, 64, 0, stream>>>(H, Hbf);
    convert_g_kernel<<<(IMGS * EMB) / 4, 256, 0, stream>>>(g, gbf);
    // ---- xapre as batched MFMA GEMM: Pbf[i*64+c][e] = Hn_i @ g_i^T ----
    gemm_gll<2, 5, 3><<<dim3(EMB / 160, 1, IMGS), 256, 0, stream>>>(
        Hbf, gbf, Pbf, CAPS, EMB, KPAD, KPAD, (long)CAPS * KPAD, (long)EMB * KPAD);
    // ---- gemm3 split-K x3: Ppart (overwrites gbf/Hbf) ----
    if (use_wbf) {
        gemm_gll<2, 5, 2><<<dim3(EMB / 160, (IMGS * CAPS) / 64, 3), 256, 0, stream>>>(
            Pbf, wbf, Ppart, IMGS * CAPS, EMB, EMB, 800, 0, 0);
    } else {
        mfma_gemm_nt<2, 3, 2, unsigned short, float>
            <<<dim3(EMB / 96, (IMGS * CAPS) / 64, 3), 256, 0, stream>>>(Pbf, fc_w, nullptr, Ppart,
                                                                        IMGS * CAPS, EMB, EMB, 800);
    }
    reduce3_kernel<<<(IMGS * CAPS * EMB / 4) / 256, 256, 0, stream>>>(Ppart, fc_b, xa_out);
    // ---- g passthrough last (overwrites all g_out scratch) ----
    hipMemcpyAsync(g_out, g, sizeof(float) * (size_t)IMGS * EMB * HW,
                   hipMemcpyDeviceToDevice, stream);
}

// Round 6
// 351.611 us; speedup vs baseline: 1.9589x; 1.0142x over previous
//
#include <hip/hip_runtime.h>
#include <math.h>

#define IMGS 16
#define EMB 2400
#define HW 196
#define CAPS 64
#define ATTK 180
#define NPOOL 15
#define NCOLS (IMGS * HW)  // 3136
#define KPAD 224           // 196 padded to multiple of 32

typedef __attribute__((ext_vector_type(8))) short short8;
typedef __attribute__((ext_vector_type(4))) float f32x4;
typedef const __attribute__((address_space(1))) unsigned int* gas1_t;
typedef __attribute__((address_space(3))) unsigned int* las3_t;

__device__ inline unsigned short f2bf(float f) {
    unsigned int u = __builtin_bit_cast(unsigned int, f);
    u += 0x7fffu + ((u >> 16) & 1u);  // round-to-nearest-even
    return (unsigned short)(u >> 16);
}
__device__ inline float bf2f(unsigned int lo16) {
    return __builtin_bit_cast(float, lo16 << 16);
}
__device__ inline unsigned umax_(unsigned a, unsigned b) { return a > b ? a : b; }
__device__ inline unsigned umin_(unsigned a, unsigned b) { return a < b ? a : b; }

// ---------------- Weldon pooling v3: sortable-int unique-id extraction ----------------
// One 64-lane wave per (img,emb) row. Values mapped to order-preserving unsigned ints,
// low 8 bits replaced by unique slot id -> knockout is a branch-free compare, no ballot.
__global__ __launch_bounds__(256) void weldon_kernel(const float* __restrict__ g,
                                                     float* __restrict__ hpool) {
    int wid = (blockIdx.x * 256 + threadIdx.x) >> 6;
    int lane = threadIdx.x & 63;
    const float* row = g + (size_t)wid * HW;
    unsigned s[4], t[4];
#pragma unroll
    for (int q = 0; q < 4; q++) {
        int e = lane + 64 * q;
        if (e < HW) {
            unsigned u = __builtin_bit_cast(unsigned, row[e]);
            int msk = ((int)u) >> 31;
            unsigned srt = u ^ (unsigned)(msk | 0x80000000);
            srt = (srt & 0xFFFFFF00u) | (unsigned)(q * 64 + lane);  // unique id
            s[q] = srt;
            t[q] = srt;
        } else {
            s[q] = 0u;            // -inf for max side
            t[q] = 0xFFFFFFFFu;   // +inf for min side
        }
    }
    float stop = 0.f, sbot = 0.f;
#pragma unroll
    for (int it = 0; it < NPOOL; ++it) {
        unsigned m = umax_(umax_(s[0], s[1]), umax_(s[2], s[3]));
#pragma unroll
        for (int d = 32; d; d >>= 1)
            m = umax_(m, (unsigned)__shfl_xor((int)m, d, 64));
        unsigned mu = (m & 0x80000000u) ? (m ^ 0x80000000u) : ~m;
        stop += __builtin_bit_cast(float, mu);
#pragma unroll
        for (int q = 0; q < 4; q++) s[q] = (s[q] == m) ? 0u : s[q];

        unsigned n = umin_(umin_(t[0], t[1]), umin_(t[2], t[3]));
#pragma unroll
        for (int d = 32; d; d >>= 1)
            n = umin_(n, (unsigned)__shfl_xor((int)n, d, 64));
        unsigned nu = (n & 0x80000000u) ? (n ^ 0x80000000u) : ~n;
        sbot += __builtin_bit_cast(float, nu);
#pragma unroll
        for (int q = 0; q < 4; q++) t[q] = (t[q] == n) ? 0xFFFFFFFFu : t[q];
    }
    if (lane == 0) hpool[wid] = (stop + sbot) / 15.0f;
}

// ---------------- x = hpool @ fc_w.T + fc_b ----------------
__global__ void x_kernel(const float* __restrict__ hpool, const float* __restrict__ fc_w,
                         const float* __restrict__ fc_b, float* __restrict__ x_out) {
    int o = blockIdx.x;
    int lane = threadIdx.x;  // 64
    float acc[IMGS];
#pragma unroll
    for (int i = 0; i < IMGS; i++) acc[i] = 0.f;
    const float* wrow = fc_w + (size_t)o * EMB;
    for (int e = lane; e < EMB; e += 64) {
        float wv = wrow[e];
#pragma unroll
        for (int i = 0; i < IMGS; i++) acc[i] += hpool[i * EMB + e] * wv;
    }
#pragma unroll
    for (int i = 0; i < IMGS; i++) {
#pragma unroll
        for (int s = 32; s > 0; s >>= 1) acc[i] += __shfl_xor(acc[i], s, 64);
    }
    if (lane == 0) {
        float bo = fc_b[o];
#pragma unroll
        for (int i = 0; i < IMGS; i++) x_out[i * EMB + o] = acc[i] + bo;
    }
}

// ---------------- top-180 per caption, rank-count, parallel over e ----------------
__global__ void topk_kernel(const float* __restrict__ caps, int* __restrict__ idxs,
                            float* __restrict__ vals) {
    __shared__ float row[EMB];
    int c = blockIdx.y;
    int tid = threadIdx.x;
    for (int e = tid; e < EMB; e += 256) row[e] = caps[(size_t)c * EMB + e];
    __syncthreads();
    int e = blockIdx.x * 256 + tid;
    if (e >= EMB) return;
    float v = row[e];
    int cnt = 0;
    for (int j = 0; j < EMB; j += 4) {
        float4 q = *(const float4*)&row[j];
        cnt += (q.x > v) || (q.x == v && (j + 0) < e);
        cnt += (q.y > v) || (q.y == v && (j + 1) < e);
        cnt += (q.z > v) || (q.z == v && (j + 2) < e);
        cnt += (q.w > v) || (q.w == v && (j + 3) < e);
    }
    if (cnt < ATTK) {
        idxs[c * ATTK + cnt] = e;
        vals[c * ATTK + cnt] = fabsf(v);
    }
}

// ---------------- fc_w fp32 -> bf16 row-major copy ----------------
__global__ void convert_w_kernel(const float* __restrict__ w, unsigned short* __restrict__ wbf) {
    int i = (blockIdx.x * 256 + threadIdx.x) * 4;
    if (i >= EMB * EMB) return;
    float4 a = *(const float4*)&w[i];
    ushort4 r;
    r.x = f2bf(a.x); r.y = f2bf(a.y); r.z = f2bf(a.z); r.w = f2bf(a.w);
    *(ushort4*)&wbf[i] = r;
}

// ---------------- gbf[i][e][KPAD] = bf16(g[i][e][hw]), zero-padded ----------------
__global__ __launch_bounds__(256) void convert_g_kernel(const float* __restrict__ g,
                                                        unsigned short* __restrict__ gbf) {
    int row = blockIdx.x * 4 + (threadIdx.x >> 6);
    int l = threadIdx.x & 63;
    const float* src = g + (size_t)row * HW;
    unsigned short* dst = gbf + (size_t)row * KPAD;
    if (l < KPAD / 4) {
        ushort4 o = {0, 0, 0, 0};
        if (l < HW / 4) {
            float4 v = ((const float4*)src)[l];
            o.x = f2bf(v.x); o.y = f2bf(v.y); o.z = f2bf(v.z); o.w = f2bf(v.w);
        }
        ((ushort4*)dst)[l] = o;
    }
}

// ---------------- gT[n][e] = bf16(g[i(n)][e][hw(n)]) ----------------
__global__ void transpose_g_kernel(const float* __restrict__ g, unsigned short* __restrict__ gT) {
    __shared__ float t[96][50];
    int i = blockIdx.z;
    int e0 = blockIdx.y * 96;
    int h0 = blockIdx.x * 49;
    int tid = threadIdx.x;
    for (int f = tid; f < 96 * 49; f += 256) {
        int e = f / 49, hh = f % 49;
        t[e][hh] = g[(size_t)i * EMB * HW + (size_t)(e0 + e) * HW + h0 + hh];
    }
    __syncthreads();
    for (int f = tid; f < 49 * 96; f += 256) {
        int hh = f / 96, e = f % 96;
        gT[(size_t)(i * HW + h0 + hh) * EMB + e0 + e] = f2bf(t[e][hh]);
    }
}

// ======== NT bf16 MFMA GEMM, global_load_lds staging, double-buffered 1-barrier loop ========
template <int MF, int NF, int OUT_MODE>
__global__ __launch_bounds__(256) void gemm_gll(const unsigned short* __restrict__ A,
                                                const unsigned short* __restrict__ B,
                                                void* __restrict__ outp,
                                                int M, int N, int K, int kper,
                                                long az, long bz) {
    constexpr int BM = MF * 32, BN = NF * 32;
    constexpr int ROWS = BM + BN;
    constexpr int NCALL = ROWS / 16;
    __shared__ unsigned short lds[2][ROWS][32];
    int m0 = blockIdx.y * BM, n0 = blockIdx.x * BN;
    int z = blockIdx.z;
    const unsigned short* Ab = A + (size_t)z * az;
    const unsigned short* Bb = B + (size_t)z * bz;
    int kb = (az == 0 && bz == 0) ? z * kper : 0;
    int nt = kper / 32;
    int tid = threadIdx.x, w = tid >> 6, lane = tid & 63;
    int wm = (w >> 1) * (MF * 16), wn = (w & 1) * (NF * 16);
    int ln = lane & 15, ks = (lane >> 4) * 8;
    int srow = lane >> 2;
    int skc = (lane & 3) * 8;

    auto STAGE = [&](int buf, int t) {
        int k0 = kb + t * 32;
        for (int j = w; j < NCALL; j += 4) {
            int r = j * 16 + srow;
            const unsigned short* src = (r < BM)
                ? (Ab + (size_t)(m0 + r) * K + k0 + skc)
                : (Bb + (size_t)(n0 + r - BM) * K + k0 + skc);
            __builtin_amdgcn_global_load_lds((gas1_t)(const void*)src,
                                             (las3_t)(void*)&lds[buf][j * 16][0], 16, 0, 0);
        }
    };

    STAGE(0, 0);
    __syncthreads();
    f32x4 acc[MF][NF] = {};
    int cur = 0;
    for (int t = 0; t < nt; ++t) {
        if (t + 1 < nt) STAGE(cur ^ 1, t + 1);
        short8 af[MF], bfv[NF];
#pragma unroll
        for (int mf = 0; mf < MF; mf++)
            af[mf] = *(const short8*)&lds[cur][wm + mf * 16 + ln][ks];
#pragma unroll
        for (int nf = 0; nf < NF; nf++)
            bfv[nf] = *(const short8*)&lds[cur][BM + wn + nf * 16 + ln][ks];
#pragma unroll
        for (int mf = 0; mf < MF; mf++)
#pragma unroll
            for (int nf = 0; nf < NF; nf++)
                acc[mf][nf] = __builtin_amdgcn_mfma_f32_16x16x32_bf16(af[mf], bfv[nf],
                                                                      acc[mf][nf], 0, 0, 0);
        __syncthreads();
        cur ^= 1;
    }
#pragma unroll
    for (int mf = 0; mf < MF; mf++) {
#pragma unroll
        for (int nf = 0; nf < NF; nf++) {
#pragma unroll
            for (int rr = 0; rr < 4; rr++) {
                int row = m0 + wm + mf * 16 + (lane >> 4) * 4 + rr;
                int col = n0 + wn + nf * 16 + ln;
                float v = acc[mf][nf][rr];
                if (OUT_MODE == 0) {
                    ((unsigned short*)outp)[(size_t)row * N + col] = f2bf(fabsf(v));
                } else if (OUT_MODE == 2) {
                    ((float*)outp)[(size_t)z * M * N + (size_t)row * N + col] = v;
                } else {
                    ((unsigned short*)outp)[(size_t)z * M * N + (size_t)row * N + col] = f2bf(v);
                }
            }
        }
    }
}

// ======== fallback reg-staged NT GEMM (used only if ws too small for wbf) ========
__device__ inline uint4 load8(const unsigned short* p) { return *(const uint4*)p; }
__device__ inline uint4 load8(const float* p) {
    float4 a = *(const float4*)p;
    float4 b = *(const float4*)(p + 4);
    uint4 r;
    r.x = (unsigned)f2bf(a.x) | ((unsigned)f2bf(a.y) << 16);
    r.y = (unsigned)f2bf(a.z) | ((unsigned)f2bf(a.w) << 16);
    r.z = (unsigned)f2bf(b.x) | ((unsigned)f2bf(b.y) << 16);
    r.w = (unsigned)f2bf(b.z) | ((unsigned)f2bf(b.w) << 16);
    return r;
}

template <int MF, int NF, int OUT_MODE, typename TA, typename TB>
__global__ __launch_bounds__(256) void mfma_gemm_nt(const TA* __restrict__ A,
                                                    const TB* __restrict__ B,
                                                    const float* __restrict__ bias,
                                                    void* __restrict__ outp,
                                                    int M, int N, int K, int kper) {
    constexpr int BM = MF * 32, BN = NF * 32;
    constexpr int nA = BM * 4, nTot = (BM + BN) * 4;
    constexpr int NCH = (nTot + 255) / 256;
    __shared__ unsigned short As[BM][40];
    __shared__ unsigned short Bs[BN][40];
    int m0 = blockIdx.y * BM, n0 = blockIdx.x * BN;
    int sk = blockIdx.z;
    int kb = sk * kper, ke = kb + kper;
    int tid = threadIdx.x;
    int w = tid >> 6, lane = tid & 63;
    int wm = (w >> 1) * (MF * 16), wn = (w & 1) * (NF * 16);
    int ln = lane & 15, ks = (lane >> 4) * 8;
    uint4 r[NCH];
#pragma unroll
    for (int j = 0; j < NCH; j++) {
        int c = tid + 256 * j;
        if (c < nTot) {
            if (c < nA) {
                int row = c >> 2, kc = c & 3;
                r[j] = load8(A + (size_t)(m0 + row) * K + kb + kc * 8);
            } else {
                int cc = c - nA, row = cc >> 2, kc = cc & 3;
                r[j] = load8(B + (size_t)(n0 + row) * K + kb + kc * 8);
            }
        }
    }
    f32x4 acc[MF][NF] = {};
    for (int k0 = kb; k0 < ke; k0 += 32) {
#pragma unroll
        for (int j = 0; j < NCH; j++) {
            int c = tid + 256 * j;
            if (c < nTot) {
                if (c < nA) {
                    int row = c >> 2, kc = c & 3;
                    *(uint4*)&As[row][kc * 8] = r[j];
                } else {
                    int cc = c - nA, row = cc >> 2, kc = cc & 3;
                    *(uint4*)&Bs[row][kc * 8] = r[j];
                }
            }
        }
        __syncthreads();
        if (k0 + 32 < ke) {
#pragma unroll
            for (int j = 0; j < NCH; j++) {
                int c = tid + 256 * j;
                if (c < nTot) {
                    if (c < nA) {
                        int row = c >> 2, kc = c & 3;
                        r[j] = load8(A + (size_t)(m0 + row) * K + (k0 + 32) + kc * 8);
                    } else {
                        int cc = c - nA, row = cc >> 2, kc = cc & 3;
                        r[j] = load8(B + (size_t)(n0 + row) * K + (k0 + 32) + kc * 8);
                    }
                }
            }
        }
        short8 af[MF], bfv[NF];
#pragma unroll
        for (int mf = 0; mf < MF; mf++)
            af[mf] = *(const short8*)&As[wm + mf * 16 + ln][ks];
#pragma unroll
        for (int nf = 0; nf < NF; nf++)
            bfv[nf] = *(const short8*)&Bs[wn + nf * 16 + ln][ks];
#pragma unroll
        for (int mf = 0; mf < MF; mf++)
#pragma unroll
            for (int nf = 0; nf < NF; nf++)
                acc[mf][nf] = __builtin_amdgcn_mfma_f32_16x16x32_bf16(af[mf], bfv[nf],
                                                                      acc[mf][nf], 0, 0, 0);
        __syncthreads();
    }
#pragma unroll
    for (int mf = 0; mf < MF; mf++) {
#pragma unroll
        for (int nf = 0; nf < NF; nf++) {
#pragma unroll
            for (int rr = 0; rr < 4; rr++) {
                int row = m0 + wm + mf * 16 + (lane >> 4) * 4 + rr;
                int col = n0 + wn + nf * 16 + ln;
                float v = acc[mf][nf][rr];
                if (OUT_MODE == 0) {
                    ((unsigned short*)outp)[(size_t)row * N + col] = f2bf(fabsf(v));
                } else if (OUT_MODE == 2) {
                    ((float*)outp)[(size_t)sk * M * N + (size_t)row * N + col] = v;
                }
            }
        }
    }
}

// ---------------- reduce 3 split-K partials + bias -> xa_out ----------------
__global__ void reduce3_kernel(const float* __restrict__ p, const float* __restrict__ bias,
                               float* __restrict__ out) {
    int i = (blockIdx.x * 256 + threadIdx.x) * 4;
    if (i >= IMGS * CAPS * EMB) return;
    float4 a = *(const float4*)&p[i];
    float4 b = *(const float4*)&p[i + IMGS * CAPS * EMB];
    float4 c = *(const float4*)&p[i + 2 * IMGS * CAPS * EMB];
    float4 bb = *(const float4*)&bias[i % EMB];
    float4 r = {a.x + b.x + c.x + bb.x, a.y + b.y + c.y + bb.y,
                a.z + b.z + c.z + bb.z, a.w + b.w + c.w + bb.w};
    *(float4*)&out[i] = r;
}

// ---------------- heat: H[c,n] = sum_j vals[c,j] * Abf[idx[c,j], n] ----------------
__global__ void heat_kernel(const int* __restrict__ idxs, const float* __restrict__ vals,
                            const unsigned short* __restrict__ A, float* __restrict__ H) {
    __shared__ int sidx[ATTK];
    __shared__ float sval[ATTK];
    int c = blockIdx.y;
    int tid = threadIdx.x;
    if (tid < ATTK) {
        sidx[tid] = idxs[c * ATTK + tid];
        sval[tid] = vals[c * ATTK + tid];
    }
    __syncthreads();
    int n = (blockIdx.x * 256 + tid) * 4;
    if (n >= NCOLS) return;
    float a0 = 0.f, a1 = 0.f, a2 = 0.f, a3 = 0.f;
    for (int j = 0; j < ATTK; j++) {
        uint2 p = *(const uint2*)&A[(size_t)sidx[j] * NCOLS + n];
        float sv = sval[j];
        a0 += sv * bf2f(p.x & 0xffffu);
        a1 += sv * bf2f(p.x >> 16);
        a2 += sv * bf2f(p.y & 0xffffu);
        a3 += sv * bf2f(p.y >> 16);
    }
    float4 r = {a0, a1, a2, a3};
    *(float4*)&H[(size_t)c * NCOLS + n] = r;
}

// ---------------- norm: Hbf[i][c][KPAD] = bf16(H / rowsum), zero-padded ----------------
__global__ void norm_kernel(const float* __restrict__ H, unsigned short* __restrict__ Hbf) {
    int c = blockIdx.x / IMGS, i = blockIdx.x % IMGS;
    const float* p = H + (size_t)c * NCOLS + i * HW;
    int lane = threadIdx.x;  // 64
    float s = 0.f;
    for (int hw = lane; hw < HW; hw += 64) s += p[hw];
#pragma unroll
    for (int d = 32; d > 0; d >>= 1) s += __shfl_xor(s, d, 64);
    float inv = 1.0f / s;
    unsigned short* dst = Hbf + ((size_t)i * CAPS + c) * KPAD;
    for (int hw = lane; hw < KPAD; hw += 64)
        dst[hw] = (hw < HW) ? f2bf(p[hw] * inv) : (unsigned short)0;
}

extern "C" void kernel_launch(void* const* d_in, const int* in_sizes, int n_in,
                              void* d_out, int out_size, void* d_ws, size_t ws_size,
                              hipStream_t stream) {
    const float* g = (const float*)d_in[0];
    const float* caps = (const float*)d_in[1];
    const float* fc_w = (const float*)d_in[2];
    const float* fc_b = (const float*)d_in[3];

    float* out = (float*)d_out;
    float* x_out = out;                    // 38400
    float* xa_out = out + 38400;           // 2457600
    float* g_out = out + 38400 + 2457600;  // 7526400 floats = 30.1 MB scratch until final copy
    unsigned short* Abf = (unsigned short*)g_out;
    unsigned short* gT = Abf + (size_t)EMB * NCOLS;
    unsigned short* gbf = (unsigned short*)g_out;
    unsigned short* Hbf = gbf + (size_t)IMGS * EMB * KPAD;
    float* Ppart = g_out;

    float* ws = (float*)d_ws;
    float* hpool = ws;                                      // 38400 f
    int* idxs = (int*)(ws + 38400);                         // 11520
    float* vals = ws + 49920;                               // 11520
    float* H = ws + 61440;                                  // 200704 f
    unsigned short* Pbf = (unsigned short*)(ws + 262144);   // ends byte 5963776
    unsigned short* wbf = (unsigned short*)(ws + 1490944);  // ends byte 17483776
    bool use_wbf = ws_size >= (size_t)17483776;

    weldon_kernel<<<(IMGS * EMB) / 4, 256, 0, stream>>>(g, hpool);
    x_kernel<<<EMB, 64, 0, stream>>>(hpool, fc_w, fc_b, x_out);
    topk_kernel<<<dim3(10, CAPS), 256, 0, stream>>>(caps, idxs, vals);
    transpose_g_kernel<<<dim3(4, 25, IMGS), 256, 0, stream>>>(g, gT);

    if (use_wbf) {
        convert_w_kernel<<<(EMB * EMB / 4 + 255) / 256, 256, 0, stream>>>(fc_w, wbf);
        gemm_gll<5, 2, 0><<<dim3(NCOLS / 64, EMB / 160, 1), 256, 0, stream>>>(
            wbf, gT, Abf, EMB, NCOLS, EMB, EMB, 0, 0);
    } else {
        mfma_gemm_nt<5, 2, 0, float, unsigned short>
            <<<dim3(NCOLS / 64, EMB / 160), 256, 0, stream>>>(fc_w, gT, nullptr, Abf,
                                                              EMB, NCOLS, EMB, EMB);
    }
    heat_kernel<<<dim3((NCOLS / 4 + 255) / 256, CAPS), 256, 0, stream>>>(idxs, vals, Abf, H);
    norm_kernel<<<CAPS * IMGS, 64, 0, stream>>>(H, Hbf);
    convert_g_kernel<<<(IMGS * EMB) / 4, 256, 0, stream>>>(g, gbf);
    gemm_gll<2, 5, 3><<<dim3(EMB / 160, 1, IMGS), 256, 0, stream>>>(
        Hbf, gbf, Pbf, CAPS, EMB, KPAD, KPAD, (long)CAPS * KPAD, (long)EMB * KPAD);
    if (use_wbf) {
        gemm_gll<2, 5, 2><<<dim3(EMB / 160, (IMGS * CAPS) / 64, 3), 256, 0, stream>>>(
            Pbf, wbf, Ppart, IMGS * CAPS, EMB, EMB, 800, 0, 0);
    } else {
        mfma_gemm_nt<2, 3, 2, unsigned short, float>
            <<<dim3(EMB / 96, (IMGS * CAPS) / 64, 3), 256, 0, stream>>>(Pbf, fc_w, nullptr, Ppart,
                                                                        IMGS * CAPS, EMB, EMB, 800);
    }
    reduce3_kernel<<<(IMGS * CAPS * EMB / 4) / 256, 256, 0, stream>>>(Ppart, fc_b, xa_out);
    hipMemcpyAsync(g_out, g, sizeof(float) * (size_t)IMGS * EMB * HW,
                   hipMemcpyDeviceToDevice, stream);
}

// Round 7
// 350.711 us; speedup vs baseline: 1.9640x; 1.0026x over previous
//
#include <hip/hip_runtime.h>
#include <math.h>

#define IMGS 16
#define EMB 2400
#define HW 196
#define CAPS 64
#define ATTK 180
#define NPOOL 15
#define NCOLS (IMGS * HW)  // 3136
#define KPAD 224           // 196 padded to multiple of 32

typedef __attribute__((ext_vector_type(8))) short short8;
typedef __attribute__((ext_vector_type(4))) float f32x4;
typedef const __attribute__((address_space(1))) unsigned int* gas1_t;
typedef __attribute__((address_space(3))) unsigned int* las3_t;
typedef unsigned long long ull;

__device__ inline unsigned short f2bf(float f) {
    unsigned int u = __builtin_bit_cast(unsigned int, f);
    u += 0x7fffu + ((u >> 16) & 1u);  // round-to-nearest-even
    return (unsigned short)(u >> 16);
}
__device__ inline float bf2f(unsigned int lo16) {
    return __builtin_bit_cast(float, lo16 << 16);
}
__device__ inline unsigned umax_(unsigned a, unsigned b) { return a > b ? a : b; }
__device__ inline unsigned umin_(unsigned a, unsigned b) { return a < b ? a : b; }
__device__ inline unsigned f2sort(float f) {
    unsigned u = __builtin_bit_cast(unsigned, f);
    int msk = ((int)u) >> 31;
    return u ^ (unsigned)(msk | 0x80000000);
}

// ---------------- Weldon pooling v3: sortable-int unique-id extraction ----------------
__global__ __launch_bounds__(256) void weldon_kernel(const float* __restrict__ g,
                                                     float* __restrict__ hpool) {
    int wid = (blockIdx.x * 256 + threadIdx.x) >> 6;
    int lane = threadIdx.x & 63;
    const float* row = g + (size_t)wid * HW;
    unsigned s[4], t[4];
#pragma unroll
    for (int q = 0; q < 4; q++) {
        int e = lane + 64 * q;
        if (e < HW) {
            unsigned srt = f2sort(row[e]);
            srt = (srt & 0xFFFFFF00u) | (unsigned)(q * 64 + lane);  // unique id
            s[q] = srt;
            t[q] = srt;
        } else {
            s[q] = 0u;
            t[q] = 0xFFFFFFFFu;
        }
    }
    float stop = 0.f, sbot = 0.f;
#pragma unroll
    for (int it = 0; it < NPOOL; ++it) {
        unsigned m = umax_(umax_(s[0], s[1]), umax_(s[2], s[3]));
#pragma unroll
        for (int d = 32; d; d >>= 1)
            m = umax_(m, (unsigned)__shfl_xor((int)m, d, 64));
        unsigned mu = (m & 0x80000000u) ? (m ^ 0x80000000u) : ~m;
        stop += __builtin_bit_cast(float, mu);
#pragma unroll
        for (int q = 0; q < 4; q++) s[q] = (s[q] == m) ? 0u : s[q];

        unsigned n = umin_(umin_(t[0], t[1]), umin_(t[2], t[3]));
#pragma unroll
        for (int d = 32; d; d >>= 1)
            n = umin_(n, (unsigned)__shfl_xor((int)n, d, 64));
        unsigned nu = (n & 0x80000000u) ? (n ^ 0x80000000u) : ~n;
        sbot += __builtin_bit_cast(float, nu);
#pragma unroll
        for (int q = 0; q < 4; q++) t[q] = (t[q] == n) ? 0xFFFFFFFFu : t[q];
    }
    if (lane == 0) hpool[wid] = (stop + sbot) / 15.0f;
}

// ---------------- x = hpool @ fc_w.T + fc_b ----------------
__global__ void x_kernel(const float* __restrict__ hpool, const float* __restrict__ fc_w,
                         const float* __restrict__ fc_b, float* __restrict__ x_out) {
    int o = blockIdx.x;
    int lane = threadIdx.x;  // 64
    float acc[IMGS];
#pragma unroll
    for (int i = 0; i < IMGS; i++) acc[i] = 0.f;
    const float* wrow = fc_w + (size_t)o * EMB;
    for (int e = lane; e < EMB; e += 64) {
        float wv = wrow[e];
#pragma unroll
        for (int i = 0; i < IMGS; i++) acc[i] += hpool[i * EMB + e] * wv;
    }
#pragma unroll
    for (int i = 0; i < IMGS; i++) {
#pragma unroll
        for (int s = 32; s > 0; s >>= 1) acc[i] += __shfl_xor(acc[i], s, 64);
    }
    if (lane == 0) {
        float bo = fc_b[o];
#pragma unroll
        for (int i = 0; i < IMGS; i++) x_out[i * EMB + o] = acc[i] + bo;
    }
}

// ---------------- topk v3: per-caption MSB radix select, O(n) ----------------
// key = (sortable(v) << 16) | ((2399-e) << 4)  -- unique; ties prefer smaller e
// 6 passes of 8 bits find the exact 180th-largest key T; selected = key >= T.
// Slot = deterministic prefix-scan in (s, tid) order (order irrelevant: heat sums).
__global__ __launch_bounds__(256) void topk_kernel(const float* __restrict__ caps,
                                                   int* __restrict__ idxs,
                                                   float* __restrict__ vals) {
    __shared__ float rowf[EMB];
    __shared__ unsigned hist[256];
    __shared__ unsigned cnts[256];
    __shared__ ull sprefix;
    __shared__ int srank;
    int c = blockIdx.x;
    int tid = threadIdx.x;
    const float4* src = (const float4*)(caps + (size_t)c * EMB);
    for (int j = tid; j < EMB / 4; j += 256) {
        float4 v = src[j];
        *(float4*)&rowf[j * 4] = v;
    }
    if (tid == 0) { sprefix = 0ull; srank = ATTK; }
    __syncthreads();

#pragma unroll 1
    for (int pass = 0; pass < 6; ++pass) {
        int shift = 40 - pass * 8;
        hist[tid] = 0;
        __syncthreads();
        ull pref = sprefix;
        ull pmaskhi = (pass == 0) ? 0ull : ~((1ull << (shift + 8)) - 1ull);
#pragma unroll 1
        for (int s = 0; s < 10; s++) {
            int e = tid + s * 256;
            if (e < EMB) {
                ull key = ((ull)f2sort(rowf[e]) << 16) | ((unsigned)(2399 - e) << 4);
                if ((key & pmaskhi) == pref)
                    atomicAdd(&hist[(unsigned)(key >> shift) & 255u], 1u);
            }
        }
        __syncthreads();
        if (tid == 0) {
            unsigned cum = 0;
            int rk = srank;
            for (int b = 255; b >= 0; --b) {
                unsigned h = hist[b];
                if (cum + h >= (unsigned)rk) {
                    srank = rk - (int)cum;
                    sprefix = pref | ((ull)b << shift);
                    break;
                }
                cum += h;
            }
        }
        __syncthreads();
    }
    ull T = sprefix;
    // selection + deterministic compaction
    unsigned selmask = 0, cnt = 0;
#pragma unroll 1
    for (int s = 0; s < 10; s++) {
        int e = tid + s * 256;
        if (e < EMB) {
            ull key = ((ull)f2sort(rowf[e]) << 16) | ((unsigned)(2399 - e) << 4);
            if (key >= T) { selmask |= 1u << s; cnt++; }
        }
    }
    cnts[tid] = cnt;
    __syncthreads();
    // Hillis-Steele inclusive scan over 256 counts
#pragma unroll
    for (int d = 1; d < 256; d <<= 1) {
        unsigned add = (tid >= d) ? cnts[tid - d] : 0u;
        __syncthreads();
        cnts[tid] += add;
        __syncthreads();
    }
    unsigned slot = cnts[tid] - cnt;
#pragma unroll 1
    for (int s = 0; s < 10; s++) {
        if (selmask & (1u << s)) {
            int e = tid + s * 256;
            idxs[c * ATTK + slot] = e;
            vals[c * ATTK + slot] = fabsf(rowf[e]);
            slot++;
        }
    }
}

// ---------------- fc_w fp32 -> bf16 row-major copy ----------------
__global__ void convert_w_kernel(const float* __restrict__ w, unsigned short* __restrict__ wbf) {
    int i = (blockIdx.x * 256 + threadIdx.x) * 4;
    if (i >= EMB * EMB) return;
    float4 a = *(const float4*)&w[i];
    ushort4 r;
    r.x = f2bf(a.x); r.y = f2bf(a.y); r.z = f2bf(a.z); r.w = f2bf(a.w);
    *(ushort4*)&wbf[i] = r;
}

// ---------------- gbf[i][e][KPAD] = bf16(g[i][e][hw]), zero-padded ----------------
__global__ __launch_bounds__(256) void convert_g_kernel(const float* __restrict__ g,
                                                        unsigned short* __restrict__ gbf) {
    int row = blockIdx.x * 4 + (threadIdx.x >> 6);
    int l = threadIdx.x & 63;
    const float* src = g + (size_t)row * HW;
    unsigned short* dst = gbf + (size_t)row * KPAD;
    if (l < KPAD / 4) {
        ushort4 o = {0, 0, 0, 0};
        if (l < HW / 4) {
            float4 v = ((const float4*)src)[l];
            o.x = f2bf(v.x); o.y = f2bf(v.y); o.z = f2bf(v.z); o.w = f2bf(v.w);
        }
        ((ushort4*)dst)[l] = o;
    }
}

// ---------------- gT[n][e] = bf16(g[i(n)][e][hw(n)]) ----------------
__global__ void transpose_g_kernel(const float* __restrict__ g, unsigned short* __restrict__ gT) {
    __shared__ float t[96][50];
    int i = blockIdx.z;
    int e0 = blockIdx.y * 96;
    int h0 = blockIdx.x * 49;
    int tid = threadIdx.x;
    for (int f = tid; f < 96 * 49; f += 256) {
        int e = f / 49, hh = f % 49;
        t[e][hh] = g[(size_t)i * EMB * HW + (size_t)(e0 + e) * HW + h0 + hh];
    }
    __syncthreads();
    for (int f = tid; f < 49 * 96; f += 256) {
        int hh = f / 96, e = f % 96;
        gT[(size_t)(i * HW + h0 + hh) * EMB + e0 + e] = f2bf(t[e][hh]);
    }
}

// ======== NT bf16 MFMA GEMM, global_load_lds staging, double-buffered 1-barrier loop ========
template <int MF, int NF, int OUT_MODE>
__global__ __launch_bounds__(256) void gemm_gll(const unsigned short* __restrict__ A,
                                                const unsigned short* __restrict__ B,
                                                void* __restrict__ outp,
                                                int M, int N, int K, int kper,
                                                long az, long bz) {
    constexpr int BM = MF * 32, BN = NF * 32;
    constexpr int ROWS = BM + BN;
    constexpr int NCALL = ROWS / 16;
    __shared__ unsigned short lds[2][ROWS][32];
    int m0 = blockIdx.y * BM, n0 = blockIdx.x * BN;
    int z = blockIdx.z;
    const unsigned short* Ab = A + (size_t)z * az;
    const unsigned short* Bb = B + (size_t)z * bz;
    int kb = (az == 0 && bz == 0) ? z * kper : 0;
    int nt = kper / 32;
    int tid = threadIdx.x, w = tid >> 6, lane = tid & 63;
    int wm = (w >> 1) * (MF * 16), wn = (w & 1) * (NF * 16);
    int ln = lane & 15, ks = (lane >> 4) * 8;
    int srow = lane >> 2;
    int skc = (lane & 3) * 8;

    auto STAGE = [&](int buf, int t) {
        int k0 = kb + t * 32;
        for (int j = w; j < NCALL; j += 4) {
            int r = j * 16 + srow;
            const unsigned short* src = (r < BM)
                ? (Ab + (size_t)(m0 + r) * K + k0 + skc)
                : (Bb + (size_t)(n0 + r - BM) * K + k0 + skc);
            __builtin_amdgcn_global_load_lds((gas1_t)(const void*)src,
                                             (las3_t)(void*)&lds[buf][j * 16][0], 16, 0, 0);
        }
    };

    STAGE(0, 0);
    __syncthreads();
    f32x4 acc[MF][NF] = {};
    int cur = 0;
    for (int t = 0; t < nt; ++t) {
        if (t + 1 < nt) STAGE(cur ^ 1, t + 1);
        short8 af[MF], bfv[NF];
#pragma unroll
        for (int mf = 0; mf < MF; mf++)
            af[mf] = *(const short8*)&lds[cur][wm + mf * 16 + ln][ks];
#pragma unroll
        for (int nf = 0; nf < NF; nf++)
            bfv[nf] = *(const short8*)&lds[cur][BM + wn + nf * 16 + ln][ks];
#pragma unroll
        for (int mf = 0; mf < MF; mf++)
#pragma unroll
            for (int nf = 0; nf < NF; nf++)
                acc[mf][nf] = __builtin_amdgcn_mfma_f32_16x16x32_bf16(af[mf], bfv[nf],
                                                                      acc[mf][nf], 0, 0, 0);
        __syncthreads();
        cur ^= 1;
    }
#pragma unroll
    for (int mf = 0; mf < MF; mf++) {
#pragma unroll
        for (int nf = 0; nf < NF; nf++) {
#pragma unroll
            for (int rr = 0; rr < 4; rr++) {
                int row = m0 + wm + mf * 16 + (lane >> 4) * 4 + rr;
                int col = n0 + wn + nf * 16 + ln;
                float v = acc[mf][nf][rr];
                if (OUT_MODE == 0) {
                    ((unsigned short*)outp)[(size_t)row * N + col] = f2bf(fabsf(v));
                } else if (OUT_MODE == 2) {
                    ((float*)outp)[(size_t)z * M * N + (size_t)row * N + col] = v;
                } else {
                    ((unsigned short*)outp)[(size_t)z * M * N + (size_t)row * N + col] = f2bf(v);
                }
            }
        }
    }
}

// ======== fallback reg-staged NT GEMM (used only if ws too small for wbf) ========
__device__ inline uint4 load8(const unsigned short* p) { return *(const uint4*)p; }
__device__ inline uint4 load8(const float* p) {
    float4 a = *(const float4*)p;
    float4 b = *(const float4*)(p + 4);
    uint4 r;
    r.x = (unsigned)f2bf(a.x) | ((unsigned)f2bf(a.y) << 16);
    r.y = (unsigned)f2bf(a.z) | ((unsigned)f2bf(a.w) << 16);
    r.z = (unsigned)f2bf(b.x) | ((unsigned)f2bf(b.y) << 16);
    r.w = (unsigned)f2bf(b.z) | ((unsigned)f2bf(b.w) << 16);
    return r;
}

template <int MF, int NF, int OUT_MODE, typename TA, typename TB>
__global__ __launch_bounds__(256) void mfma_gemm_nt(const TA* __restrict__ A,
                                                    const TB* __restrict__ B,
                                                    const float* __restrict__ bias,
                                                    void* __restrict__ outp,
                                                    int M, int N, int K, int kper) {
    constexpr int BM = MF * 32, BN = NF * 32;
    constexpr int nA = BM * 4, nTot = (BM + BN) * 4;
    constexpr int NCH = (nTot + 255) / 256;
    __shared__ unsigned short As[BM][40];
    __shared__ unsigned short Bs[BN][40];
    int m0 = blockIdx.y * BM, n0 = blockIdx.x * BN;
    int sk = blockIdx.z;
    int kb = sk * kper, ke = kb + kper;
    int tid = threadIdx.x;
    int w = tid >> 6, lane = tid & 63;
    int wm = (w >> 1) * (MF * 16), wn = (w & 1) * (NF * 16);
    int ln = lane & 15, ks = (lane >> 4) * 8;
    uint4 r[NCH];
#pragma unroll
    for (int j = 0; j < NCH; j++) {
        int c = tid + 256 * j;
        if (c < nTot) {
            if (c < nA) {
                int row = c >> 2, kc = c & 3;
                r[j] = load8(A + (size_t)(m0 + row) * K + kb + kc * 8);
            } else {
                int cc = c - nA, row = cc >> 2, kc = cc & 3;
                r[j] = load8(B + (size_t)(n0 + row) * K + kb + kc * 8);
            }
        }
    }
    f32x4 acc[MF][NF] = {};
    for (int k0 = kb; k0 < ke; k0 += 32) {
#pragma unroll
        for (int j = 0; j < NCH; j++) {
            int c = tid + 256 * j;
            if (c < nTot) {
                if (c < nA) {
                    int row = c >> 2, kc = c & 3;
                    *(uint4*)&As[row][kc * 8] = r[j];
                } else {
                    int cc = c - nA, row = cc >> 2, kc = cc & 3;
                    *(uint4*)&Bs[row][kc * 8] = r[j];
                }
            }
        }
        __syncthreads();
        if (k0 + 32 < ke) {
#pragma unroll
            for (int j = 0; j < NCH; j++) {
                int c = tid + 256 * j;
                if (c < nTot) {
                    if (c < nA) {
                        int row = c >> 2, kc = c & 3;
                        r[j] = load8(A + (size_t)(m0 + row) * K + (k0 + 32) + kc * 8);
                    } else {
                        int cc = c - nA, row = cc >> 2, kc = cc & 3;
                        r[j] = load8(B + (size_t)(n0 + row) * K + (k0 + 32) + kc * 8);
                    }
                }
            }
        }
        short8 af[MF], bfv[NF];
#pragma unroll
        for (int mf = 0; mf < MF; mf++)
            af[mf] = *(const short8*)&As[wm + mf * 16 + ln][ks];
#pragma unroll
        for (int nf = 0; nf < NF; nf++)
            bfv[nf] = *(const short8*)&Bs[wn + nf * 16 + ln][ks];
#pragma unroll
        for (int mf = 0; mf < MF; mf++)
#pragma unroll
            for (int nf = 0; nf < NF; nf++)
                acc[mf][nf] = __builtin_amdgcn_mfma_f32_16x16x32_bf16(af[mf], bfv[nf],
                                                                      acc[mf][nf], 0, 0, 0);
        __syncthreads();
    }
#pragma unroll
    for (int mf = 0; mf < MF; mf++) {
#pragma unroll
        for (int nf = 0; nf < NF; nf++) {
#pragma unroll
            for (int rr = 0; rr < 4; rr++) {
                int row = m0 + wm + mf * 16 + (lane >> 4) * 4 + rr;
                int col = n0 + wn + nf * 16 + ln;
                float v = acc[mf][nf][rr];
                if (OUT_MODE == 0) {
                    ((unsigned short*)outp)[(size_t)row * N + col] = f2bf(fabsf(v));
                } else if (OUT_MODE == 2) {
                    ((float*)outp)[(size_t)sk * M * N + (size_t)row * N + col] = v;
                }
            }
        }
    }
}

// ---------------- reduce 3 split-K partials + bias -> xa_out ----------------
__global__ void reduce3_kernel(const float* __restrict__ p, const float* __restrict__ bias,
                               float* __restrict__ out) {
    int i = (blockIdx.x * 256 + threadIdx.x) * 4;
    if (i >= IMGS * CAPS * EMB) return;
    float4 a = *(const float4*)&p[i];
    float4 b = *(const float4*)&p[i + IMGS * CAPS * EMB];
    float4 c = *(const float4*)&p[i + 2 * IMGS * CAPS * EMB];
    float4 bb = *(const float4*)&bias[i % EMB];
    float4 r = {a.x + b.x + c.x + bb.x, a.y + b.y + c.y + bb.y,
                a.z + b.z + c.z + bb.z, a.w + b.w + c.w + bb.w};
    *(float4*)&out[i] = r;
}

// ---------------- heat: H[c,n] = sum_j vals[c,j] * Abf[idx[c,j], n] ----------------
__global__ void heat_kernel(const int* __restrict__ idxs, const float* __restrict__ vals,
                            const unsigned short* __restrict__ A, float* __restrict__ H) {
    __shared__ int sidx[ATTK];
    __shared__ float sval[ATTK];
    int c = blockIdx.y;
    int tid = threadIdx.x;
    if (tid < ATTK) {
        sidx[tid] = idxs[c * ATTK + tid];
        sval[tid] = vals[c * ATTK + tid];
    }
    __syncthreads();
    int n = (blockIdx.x * 256 + tid) * 4;
    if (n >= NCOLS) return;
    float a0 = 0.f, a1 = 0.f, a2 = 0.f, a3 = 0.f;
    for (int j = 0; j < ATTK; j++) {
        uint2 p = *(const uint2*)&A[(size_t)sidx[j] * NCOLS + n];
        float sv = sval[j];
        a0 += sv * bf2f(p.x & 0xffffu);
        a1 += sv * bf2f(p.x >> 16);
        a2 += sv * bf2f(p.y & 0xffffu);
        a3 += sv * bf2f(p.y >> 16);
    }
    float4 r = {a0, a1, a2, a3};
    *(float4*)&H[(size_t)c * NCOLS + n] = r;
}

// ---------------- norm: Hbf[i][c][KPAD] = bf16(H / rowsum), zero-padded ----------------
__global__ void norm_kernel(const float* __restrict__ H, unsigned short* __restrict__ Hbf) {
    int c = blockIdx.x / IMGS, i = blockIdx.x % IMGS;
    const float* p = H + (size_t)c * NCOLS + i * HW;
    int lane = threadIdx.x;  // 64
    float s = 0.f;
    for (int hw = lane; hw < HW; hw += 64) s += p[hw];
#pragma unroll
    for (int d = 32; d > 0; d >>= 1) s += __shfl_xor(s, d, 64);
    float inv = 1.0f / s;
    unsigned short* dst = Hbf + ((size_t)i * CAPS + c) * KPAD;
    for (int hw = lane; hw < KPAD; hw += 64)
        dst[hw] = (hw < HW) ? f2bf(p[hw] * inv) : (unsigned short)0;
}

extern "C" void kernel_launch(void* const* d_in, const int* in_sizes, int n_in,
                              void* d_out, int out_size, void* d_ws, size_t ws_size,
                              hipStream_t stream) {
    const float* g = (const float*)d_in[0];
    const float* caps = (const float*)d_in[1];
    const float* fc_w = (const float*)d_in[2];
    const float* fc_b = (const float*)d_in[3];

    float* out = (float*)d_out;
    float* x_out = out;                    // 38400
    float* xa_out = out + 38400;           // 2457600
    float* g_out = out + 38400 + 2457600;  // 7526400 floats = 30.1 MB scratch until final copy
    unsigned short* Abf = (unsigned short*)g_out;
    unsigned short* gT = Abf + (size_t)EMB * NCOLS;
    unsigned short* gbf = (unsigned short*)g_out;
    unsigned short* Hbf = gbf + (size_t)IMGS * EMB * KPAD;
    float* Ppart = g_out;

    float* ws = (float*)d_ws;
    float* hpool = ws;                                      // 38400 f
    int* idxs = (int*)(ws + 38400);                         // 11520
    float* vals = ws + 49920;                               // 11520
    float* H = ws + 61440;                                  // 200704 f
    unsigned short* Pbf = (unsigned short*)(ws + 262144);   // ends byte 5963776
    unsigned short* wbf = (unsigned short*)(ws + 1490944);  // ends byte 17483776
    bool use_wbf = ws_size >= (size_t)17483776;

    weldon_kernel<<<(IMGS * EMB) / 4, 256, 0, stream>>>(g, hpool);
    x_kernel<<<EMB, 64, 0, stream>>>(hpool, fc_w, fc_b, x_out);
    topk_kernel<<<CAPS, 256, 0, stream>>>(caps, idxs, vals);
    transpose_g_kernel<<<dim3(4, 25, IMGS), 256, 0, stream>>>(g, gT);

    if (use_wbf) {
        convert_w_kernel<<<(EMB * EMB / 4 + 255) / 256, 256, 0, stream>>>(fc_w, wbf);
        gemm_gll<5, 2, 0><<<dim3(NCOLS / 64, EMB / 160, 1), 256, 0, stream>>>(
            wbf, gT, Abf, EMB, NCOLS, EMB, EMB, 0, 0);
    } else {
        mfma_gemm_nt<5, 2, 0, float, unsigned short>
            <<<dim3(NCOLS / 64, EMB / 160), 256, 0, stream>>>(fc_w, gT, nullptr, Abf,
                                                              EMB, NCOLS, EMB, EMB);
    }
    heat_kernel<<<dim3((NCOLS / 4 + 255) / 256, CAPS), 256, 0, stream>>>(idxs, vals, Abf, H);
    norm_kernel<<<CAPS * IMGS, 64, 0, stream>>>(H, Hbf);
    convert_g_kernel<<<(IMGS * EMB) / 4, 256, 0, stream>>>(g, gbf);
    gemm_gll<2, 5, 3><<<dim3(EMB / 160, 1, IMGS), 256, 0, stream>>>(
        Hbf, gbf, Pbf, CAPS, EMB, KPAD, KPAD, (long)CAPS * KPAD, (long)EMB * KPAD);
    if (use_wbf) {
        gemm_gll<2, 5, 2><<<dim3(EMB / 160, (IMGS * CAPS) / 64, 3), 256, 0, stream>>>(
            Pbf, wbf, Ppart, IMGS * CAPS, EMB, EMB, 800, 0, 0);
    } else {
        mfma_gemm_nt<2, 3, 2, unsigned short, float>
            <<<dim3(EMB / 96, (IMGS * CAPS) / 64, 3), 256, 0, stream>>>(Pbf, fc_w, nullptr, Ppart,
                                                                        IMGS * CAPS, EMB, EMB, 800);
    }
    reduce3_kernel<<<(IMGS * CAPS * EMB / 4) / 256, 256, 0, stream>>>(Ppart, fc_b, xa_out);
    hipMemcpyAsync(g_out, g, sizeof(float) * (size_t)IMGS * EMB * HW,
                   hipMemcpyDeviceToDevice, stream);
}

// Round 8
// 274.349 us; speedup vs baseline: 2.5106x; 1.2783x over previous
//
#include <hip/hip_runtime.h>
#include <math.h>

#define IMGS 16
#define EMB 2400
#define HW 196
#define CAPS 64
#define ATTK 180
#define NPOOL 15
#define NCOLS (IMGS * HW)  // 3136
#define KPAD 224           // 196 padded to multiple of 32

typedef __attribute__((ext_vector_type(8))) short short8;
typedef __attribute__((ext_vector_type(4))) float f32x4;
typedef const __attribute__((address_space(1))) unsigned int* gas1_t;
typedef __attribute__((address_space(3))) unsigned int* las3_t;
typedef unsigned long long ull;

__device__ inline unsigned short f2bf(float f) {
    unsigned int u = __builtin_bit_cast(unsigned int, f);
    u += 0x7fffu + ((u >> 16) & 1u);  // round-to-nearest-even
    return (unsigned short)(u >> 16);
}
__device__ inline float bf2f(unsigned int lo16) {
    return __builtin_bit_cast(float, lo16 << 16);
}
__device__ inline unsigned f2sort(float f) {
    unsigned u = __builtin_bit_cast(unsigned, f);
    int msk = ((int)u) >> 31;
    return u ^ (unsigned)(msk | 0x80000000);
}

// ---- DPP 64-lane reductions (rocPRIM pattern): row_shr 1/2/4/8 + row_bcast 15/31 ----
// Result broadcast via readlane(63). No DS ops, no address VALU.
__device__ inline float wave_max64_dpp(float v) {
    int x = __builtin_bit_cast(int, v);
#define STEPMX(c)                                                              \
    {                                                                          \
        int y = __builtin_amdgcn_update_dpp(x, x, c, 0xf, 0xf, false);         \
        float a = fmaxf(__builtin_bit_cast(float, x), __builtin_bit_cast(float, y)); \
        x = __builtin_bit_cast(int, a);                                        \
    }
    STEPMX(0x111) STEPMX(0x112) STEPMX(0x114) STEPMX(0x118) STEPMX(0x142) STEPMX(0x143)
#undef STEPMX
    return __builtin_bit_cast(float, __builtin_amdgcn_readlane(x, 63));
}
__device__ inline float wave_min64_dpp(float v) {
    int x = __builtin_bit_cast(int, v);
#define STEPMN(c)                                                              \
    {                                                                          \
        int y = __builtin_amdgcn_update_dpp(x, x, c, 0xf, 0xf, false);         \
        float a = fminf(__builtin_bit_cast(float, x), __builtin_bit_cast(float, y)); \
        x = __builtin_bit_cast(int, a);                                        \
    }
    STEPMN(0x111) STEPMN(0x112) STEPMN(0x114) STEPMN(0x118) STEPMN(0x142) STEPMN(0x143)
#undef STEPMN
    return __builtin_bit_cast(float, __builtin_amdgcn_readlane(x, 63));
}

// ---------------- Weldon pooling v4: DPP reduce + unique-id floats ----------------
// Values kept as floats with the low 8 mantissa bits replaced by a unique slot id
// (perturbation <= 2^-16 rel; ids make every element bit-unique so knockout is a
// branch-free bit-compare). Max/min chains are independent; 15 extractions each.
__global__ __launch_bounds__(256) void weldon_kernel(const float* __restrict__ g,
                                                     float* __restrict__ hpool) {
    int wid = (blockIdx.x * 256 + threadIdx.x) >> 6;
    int lane = threadIdx.x & 63;
    const float* row = g + (size_t)wid * HW;
    float s[4], t[4];
#pragma unroll
    for (int q = 0; q < 4; q++) {
        int e = lane + 64 * q;
        if (e < HW) {
            unsigned u = __builtin_bit_cast(unsigned, row[e]);
            u = (u & 0xFFFFFF00u) | (unsigned)(q * 64 + lane);
            float f = __builtin_bit_cast(float, u);
            s[q] = f;
            t[q] = f;
        } else {
            s[q] = -INFINITY;
            t[q] = INFINITY;
        }
    }
    float stop = 0.f, sbot = 0.f;
#pragma unroll
    for (int it = 0; it < NPOOL; ++it) {
        float m = wave_max64_dpp(fmaxf(fmaxf(s[0], s[1]), fmaxf(s[2], s[3])));
        stop += m;
        unsigned mb = __builtin_bit_cast(unsigned, m);
#pragma unroll
        for (int q = 0; q < 4; q++)
            s[q] = (__builtin_bit_cast(unsigned, s[q]) == mb) ? -INFINITY : s[q];

        float n = wave_min64_dpp(fminf(fminf(t[0], t[1]), fminf(t[2], t[3])));
        sbot += n;
        unsigned nb = __builtin_bit_cast(unsigned, n);
#pragma unroll
        for (int q = 0; q < 4; q++)
            t[q] = (__builtin_bit_cast(unsigned, t[q]) == nb) ? INFINITY : t[q];
    }
    if (lane == 0) hpool[wid] = (stop + sbot) / 15.0f;
}

// ---------------- x = hpool @ fc_w.T + fc_b ----------------
__global__ void x_kernel(const float* __restrict__ hpool, const float* __restrict__ fc_w,
                         const float* __restrict__ fc_b, float* __restrict__ x_out) {
    int o = blockIdx.x;
    int lane = threadIdx.x;  // 64
    float acc[IMGS];
#pragma unroll
    for (int i = 0; i < IMGS; i++) acc[i] = 0.f;
    const float* wrow = fc_w + (size_t)o * EMB;
    for (int e = lane; e < EMB; e += 64) {
        float wv = wrow[e];
#pragma unroll
        for (int i = 0; i < IMGS; i++) acc[i] += hpool[i * EMB + e] * wv;
    }
#pragma unroll
    for (int i = 0; i < IMGS; i++) {
#pragma unroll
        for (int s = 32; s > 0; s >>= 1) acc[i] += __shfl_xor(acc[i], s, 64);
    }
    if (lane == 0) {
        float bo = fc_b[o];
#pragma unroll
        for (int i = 0; i < IMGS; i++) x_out[i * EMB + o] = acc[i] + bo;
    }
}

// ---------------- topk v4: radix select with PARALLEL bucket scan ----------------
// key = (sortable(v) << 16) | ((2399-e) << 4); 6x8-bit MSB passes.
// Per-wave histograms (4x less atomic contention) + 256-thread reversed
// Hillis-Steele scan replaces the serial 256-bucket walk (r7: 77us serial).
__global__ __launch_bounds__(256) void topk_kernel(const float* __restrict__ caps,
                                                   int* __restrict__ idxs,
                                                   float* __restrict__ vals) {
    __shared__ float rowf[EMB];
    __shared__ unsigned hist[4][256];
    __shared__ unsigned scanbuf[256];
    __shared__ unsigned cnts[256];
    __shared__ ull sprefix;
    __shared__ int srank;
    int c = blockIdx.x;
    int tid = threadIdx.x;
    const float4* src = (const float4*)(caps + (size_t)c * EMB);
    for (int j = tid; j < EMB / 4; j += 256) {
        float4 v = src[j];
        *(float4*)&rowf[j * 4] = v;
    }
    if (tid == 0) { sprefix = 0ull; srank = ATTK; }

#pragma unroll 1
    for (int pass = 0; pass < 6; ++pass) {
        __syncthreads();  // previous pass's sprefix/srank visible
        ull pref = sprefix;
        int rk = srank;
        int shift = 40 - pass * 8;
        ull pmaskhi = (pass == 0) ? 0ull : ~((1ull << (shift + 8)) - 1ull);
        hist[0][tid] = 0; hist[1][tid] = 0; hist[2][tid] = 0; hist[3][tid] = 0;
        __syncthreads();
        unsigned* myhist = hist[tid >> 6];
#pragma unroll 1
        for (int s = 0; s < 10; s++) {
            int e = tid + s * 256;
            if (e < EMB) {
                ull key = ((ull)f2sort(rowf[e]) << 16) | ((unsigned)(2399 - e) << 4);
                if ((key & pmaskhi) == pref)
                    atomicAdd(&myhist[(unsigned)(key >> shift) & 255u], 1u);
            }
        }
        __syncthreads();
        unsigned h = hist[0][tid] + hist[1][tid] + hist[2][tid] + hist[3][tid];
        scanbuf[255 - tid] = h;
        __syncthreads();
#pragma unroll
        for (int d = 1; d < 256; d <<= 1) {
            unsigned add = (tid >= d) ? scanbuf[tid - d] : 0u;
            __syncthreads();
            scanbuf[tid] += add;
            __syncthreads();
        }
        unsigned incl = scanbuf[255 - tid];  // sum of h over buckets >= tid
        unsigned excl = incl - h;            // sum over buckets > tid
        if (h > 0u && excl < (unsigned)rk && incl >= (unsigned)rk) {
            srank = rk - (int)excl;
            sprefix = pref | ((ull)tid << shift);
        }
    }
    __syncthreads();
    ull T = sprefix;  // exact 180th-largest key
    unsigned selmask = 0, cnt = 0;
#pragma unroll 1
    for (int s = 0; s < 10; s++) {
        int e = tid + s * 256;
        if (e < EMB) {
            ull key = ((ull)f2sort(rowf[e]) << 16) | ((unsigned)(2399 - e) << 4);
            if (key >= T) { selmask |= 1u << s; cnt++; }
        }
    }
    cnts[tid] = cnt;
    __syncthreads();
#pragma unroll
    for (int d = 1; d < 256; d <<= 1) {
        unsigned add = (tid >= d) ? cnts[tid - d] : 0u;
        __syncthreads();
        cnts[tid] += add;
        __syncthreads();
    }
    unsigned slot = cnts[tid] - cnt;
#pragma unroll 1
    for (int s = 0; s < 10; s++) {
        if (selmask & (1u << s)) {
            int e = tid + s * 256;
            idxs[c * ATTK + slot] = e;
            vals[c * ATTK + slot] = fabsf(rowf[e]);
            slot++;
        }
    }
}

// ---------------- fc_w fp32 -> bf16 row-major copy ----------------
__global__ void convert_w_kernel(const float* __restrict__ w, unsigned short* __restrict__ wbf) {
    int i = (blockIdx.x * 256 + threadIdx.x) * 4;
    if (i >= EMB * EMB) return;
    float4 a = *(const float4*)&w[i];
    ushort4 r;
    r.x = f2bf(a.x); r.y = f2bf(a.y); r.z = f2bf(a.z); r.w = f2bf(a.w);
    *(ushort4*)&wbf[i] = r;
}

// ---------------- gbf[i][e][KPAD] = bf16(g[i][e][hw]), zero-padded ----------------
__global__ __launch_bounds__(256) void convert_g_kernel(const float* __restrict__ g,
                                                        unsigned short* __restrict__ gbf) {
    int row = blockIdx.x * 4 + (threadIdx.x >> 6);
    int l = threadIdx.x & 63;
    const float* src = g + (size_t)row * HW;
    unsigned short* dst = gbf + (size_t)row * KPAD;
    if (l < KPAD / 4) {
        ushort4 o = {0, 0, 0, 0};
        if (l < HW / 4) {
            float4 v = ((const float4*)src)[l];
            o.x = f2bf(v.x); o.y = f2bf(v.y); o.z = f2bf(v.z); o.w = f2bf(v.w);
        }
        ((ushort4*)dst)[l] = o;
    }
}

// ---------------- gT[n][e] = bf16(g[i(n)][e][hw(n)]) ----------------
__global__ void transpose_g_kernel(const float* __restrict__ g, unsigned short* __restrict__ gT) {
    __shared__ float t[96][50];
    int i = blockIdx.z;
    int e0 = blockIdx.y * 96;
    int h0 = blockIdx.x * 49;
    int tid = threadIdx.x;
    for (int f = tid; f < 96 * 49; f += 256) {
        int e = f / 49, hh = f % 49;
        t[e][hh] = g[(size_t)i * EMB * HW + (size_t)(e0 + e) * HW + h0 + hh];
    }
    __syncthreads();
    for (int f = tid; f < 49 * 96; f += 256) {
        int hh = f / 96, e = f % 96;
        gT[(size_t)(i * HW + h0 + hh) * EMB + e0 + e] = f2bf(t[e][hh]);
    }
}

// ======== NT bf16 MFMA GEMM, global_load_lds staging, double-buffered 1-barrier loop ========
template <int MF, int NF, int OUT_MODE>
__global__ __launch_bounds__(256) void gemm_gll(const unsigned short* __restrict__ A,
                                                const unsigned short* __restrict__ B,
                                                void* __restrict__ outp,
                                                int M, int N, int K, int kper,
                                                long az, long bz) {
    constexpr int BM = MF * 32, BN = NF * 32;
    constexpr int ROWS = BM + BN;
    constexpr int NCALL = ROWS / 16;
    __shared__ unsigned short lds[2][ROWS][32];
    int m0 = blockIdx.y * BM, n0 = blockIdx.x * BN;
    int z = blockIdx.z;
    const unsigned short* Ab = A + (size_t)z * az;
    const unsigned short* Bb = B + (size_t)z * bz;
    int kb = (az == 0 && bz == 0) ? z * kper : 0;
    int nt = kper / 32;
    int tid = threadIdx.x, w = tid >> 6, lane = tid & 63;
    int wm = (w >> 1) * (MF * 16), wn = (w & 1) * (NF * 16);
    int ln = lane & 15, ks = (lane >> 4) * 8;
    int srow = lane >> 2;
    int skc = (lane & 3) * 8;

    auto STAGE = [&](int buf, int t) {
        int k0 = kb + t * 32;
        for (int j = w; j < NCALL; j += 4) {
            int r = j * 16 + srow;
            const unsigned short* src = (r < BM)
                ? (Ab + (size_t)(m0 + r) * K + k0 + skc)
                : (Bb + (size_t)(n0 + r - BM) * K + k0 + skc);
            __builtin_amdgcn_global_load_lds((gas1_t)(const void*)src,
                                             (las3_t)(void*)&lds[buf][j * 16][0], 16, 0, 0);
        }
    };

    STAGE(0, 0);
    __syncthreads();
    f32x4 acc[MF][NF] = {};
    int cur = 0;
    for (int t = 0; t < nt; ++t) {
        if (t + 1 < nt) STAGE(cur ^ 1, t + 1);
        short8 af[MF], bfv[NF];
#pragma unroll
        for (int mf = 0; mf < MF; mf++)
            af[mf] = *(const short8*)&lds[cur][wm + mf * 16 + ln][ks];
#pragma unroll
        for (int nf = 0; nf < NF; nf++)
            bfv[nf] = *(const short8*)&lds[cur][BM + wn + nf * 16 + ln][ks];
#pragma unroll
        for (int mf = 0; mf < MF; mf++)
#pragma unroll
            for (int nf = 0; nf < NF; nf++)
                acc[mf][nf] = __builtin_amdgcn_mfma_f32_16x16x32_bf16(af[mf], bfv[nf],
                                                                      acc[mf][nf], 0, 0, 0);
        __syncthreads();
        cur ^= 1;
    }
#pragma unroll
    for (int mf = 0; mf < MF; mf++) {
#pragma unroll
        for (int nf = 0; nf < NF; nf++) {
#pragma unroll
            for (int rr = 0; rr < 4; rr++) {
                int row = m0 + wm + mf * 16 + (lane >> 4) * 4 + rr;
                int col = n0 + wn + nf * 16 + ln;
                float v = acc[mf][nf][rr];
                if (OUT_MODE == 0) {
                    ((unsigned short*)outp)[(size_t)row * N + col] = f2bf(fabsf(v));
                } else if (OUT_MODE == 2) {
                    ((float*)outp)[(size_t)z * M * N + (size_t)row * N + col] = v;
                } else {
                    ((unsigned short*)outp)[(size_t)z * M * N + (size_t)row * N + col] = f2bf(v);
                }
            }
        }
    }
}

// ======== fallback reg-staged NT GEMM (used only if ws too small for wbf) ========
__device__ inline uint4 load8(const unsigned short* p) { return *(const uint4*)p; }
__device__ inline uint4 load8(const float* p) {
    float4 a = *(const float4*)p;
    float4 b = *(const float4*)(p + 4);
    uint4 r;
    r.x = (unsigned)f2bf(a.x) | ((unsigned)f2bf(a.y) << 16);
    r.y = (unsigned)f2bf(a.z) | ((unsigned)f2bf(a.w) << 16);
    r.z = (unsigned)f2bf(b.x) | ((unsigned)f2bf(b.y) << 16);
    r.w = (unsigned)f2bf(b.z) | ((unsigned)f2bf(b.w) << 16);
    return r;
}

template <int MF, int NF, int OUT_MODE, typename TA, typename TB>
__global__ __launch_bounds__(256) void mfma_gemm_nt(const TA* __restrict__ A,
                                                    const TB* __restrict__ B,
                                                    const float* __restrict__ bias,
                                                    void* __restrict__ outp,
                                                    int M, int N, int K, int kper) {
    constexpr int BM = MF * 32, BN = NF * 32;
    constexpr int nA = BM * 4, nTot = (BM + BN) * 4;
    constexpr int NCH = (nTot + 255) / 256;
    __shared__ unsigned short As[BM][40];
    __shared__ unsigned short Bs[BN][40];
    int m0 = blockIdx.y * BM, n0 = blockIdx.x * BN;
    int sk = blockIdx.z;
    int kb = sk * kper, ke = kb + kper;
    int tid = threadIdx.x;
    int w = tid >> 6, lane = tid & 63;
    int wm = (w >> 1) * (MF * 16), wn = (w & 1) * (NF * 16);
    int ln = lane & 15, ks = (lane >> 4) * 8;
    uint4 r[NCH];
#pragma unroll
    for (int j = 0; j < NCH; j++) {
        int c = tid + 256 * j;
        if (c < nTot) {
            if (c < nA) {
                int row = c >> 2, kc = c & 3;
                r[j] = load8(A + (size_t)(m0 + row) * K + kb + kc * 8);
            } else {
                int cc = c - nA, row = cc >> 2, kc = cc & 3;
                r[j] = load8(B + (size_t)(n0 + row) * K + kb + kc * 8);
            }
        }
    }
    f32x4 acc[MF][NF] = {};
    for (int k0 = kb; k0 < ke; k0 += 32) {
#pragma unroll
        for (int j = 0; j < NCH; j++) {
            int c = tid + 256 * j;
            if (c < nTot) {
                if (c < nA) {
                    int row = c >> 2, kc = c & 3;
                    *(uint4*)&As[row][kc * 8] = r[j];
                } else {
                    int cc = c - nA, row = cc >> 2, kc = cc & 3;
                    *(uint4*)&Bs[row][kc * 8] = r[j];
                }
            }
        }
        __syncthreads();
        if (k0 + 32 < ke) {
#pragma unroll
            for (int j = 0; j < NCH; j++) {
                int c = tid + 256 * j;
                if (c < nTot) {
                    if (c < nA) {
                        int row = c >> 2, kc = c & 3;
                        r[j] = load8(A + (size_t)(m0 + row) * K + (k0 + 32) + kc * 8);
                    } else {
                        int cc = c - nA, row = cc >> 2, kc = cc & 3;
                        r[j] = load8(B + (size_t)(n0 + row) * K + (k0 + 32) + kc * 8);
                    }
                }
            }
        }
        short8 af[MF], bfv[NF];
#pragma unroll
        for (int mf = 0; mf < MF; mf++)
            af[mf] = *(const short8*)&As[wm + mf * 16 + ln][ks];
#pragma unroll
        for (int nf = 0; nf < NF; nf++)
            bfv[nf] = *(const short8*)&Bs[wn + nf * 16 + ln][ks];
#pragma unroll
        for (int mf = 0; mf < MF; mf++)
#pragma unroll
            for (int nf = 0; nf < NF; nf++)
                acc[mf][nf] = __builtin_amdgcn_mfma_f32_16x16x32_bf16(af[mf], bfv[nf],
                                                                      acc[mf][nf], 0, 0, 0);
        __syncthreads();
    }
#pragma unroll
    for (int mf = 0; mf < MF; mf++) {
#pragma unroll
        for (int nf = 0; nf < NF; nf++) {
#pragma unroll
            for (int rr = 0; rr < 4; rr++) {
                int row = m0 + wm + mf * 16 + (lane >> 4) * 4 + rr;
                int col = n0 + wn + nf * 16 + ln;
                float v = acc[mf][nf][rr];
                if (OUT_MODE == 0) {
                    ((unsigned short*)outp)[(size_t)row * N + col] = f2bf(fabsf(v));
                } else if (OUT_MODE == 2) {
                    ((float*)outp)[(size_t)sk * M * N + (size_t)row * N + col] = v;
                }
            }
        }
    }
}

// ---------------- reduce 3 split-K partials + bias -> xa_out ----------------
__global__ void reduce3_kernel(const float* __restrict__ p, const float* __restrict__ bias,
                               float* __restrict__ out) {
    int i = (blockIdx.x * 256 + threadIdx.x) * 4;
    if (i >= IMGS * CAPS * EMB) return;
    float4 a = *(const float4*)&p[i];
    float4 b = *(const float4*)&p[i + IMGS * CAPS * EMB];
    float4 c = *(const float4*)&p[i + 2 * IMGS * CAPS * EMB];
    float4 bb = *(const float4*)&bias[i % EMB];
    float4 r = {a.x + b.x + c.x + bb.x, a.y + b.y + c.y + bb.y,
                a.z + b.z + c.z + bb.z, a.w + b.w + c.w + bb.w};
    *(float4*)&out[i] = r;
}

// ---------------- heat: H[c,n] = sum_j vals[c,j] * Abf[idx[c,j], n] ----------------
__global__ void heat_kernel(const int* __restrict__ idxs, const float* __restrict__ vals,
                            const unsigned short* __restrict__ A, float* __restrict__ H) {
    __shared__ int sidx[ATTK];
    __shared__ float sval[ATTK];
    int c = blockIdx.y;
    int tid = threadIdx.x;
    if (tid < ATTK) {
        sidx[tid] = idxs[c * ATTK + tid];
        sval[tid] = vals[c * ATTK + tid];
    }
    __syncthreads();
    int n = (blockIdx.x * 256 + tid) * 4;
    if (n >= NCOLS) return;
    float a0 = 0.f, a1 = 0.f, a2 = 0.f, a3 = 0.f;
    for (int j = 0; j < ATTK; j++) {
        uint2 p = *(const uint2*)&A[(size_t)sidx[j] * NCOLS + n];
        float sv = sval[j];
        a0 += sv * bf2f(p.x & 0xffffu);
        a1 += sv * bf2f(p.x >> 16);
        a2 += sv * bf2f(p.y & 0xffffu);
        a3 += sv * bf2f(p.y >> 16);
    }
    float4 r = {a0, a1, a2, a3};
    *(float4*)&H[(size_t)c * NCOLS + n] = r;
}

// ---------------- norm: Hbf[i][c][KPAD] = bf16(H / rowsum), zero-padded ----------------
__global__ void norm_kernel(const float* __restrict__ H, unsigned short* __restrict__ Hbf) {
    int c = blockIdx.x / IMGS, i = blockIdx.x % IMGS;
    const float* p = H + (size_t)c * NCOLS + i * HW;
    int lane = threadIdx.x;  // 64
    float s = 0.f;
    for (int hw = lane; hw < HW; hw += 64) s += p[hw];
#pragma unroll
    for (int d = 32; d > 0; d >>= 1) s += __shfl_xor(s, d, 64);
    float inv = 1.0f / s;
    unsigned short* dst = Hbf + ((size_t)i * CAPS + c) * KPAD;
    for (int hw = lane; hw < KPAD; hw += 64)
        dst[hw] = (hw < HW) ? f2bf(p[hw] * inv) : (unsigned short)0;
}

extern "C" void kernel_launch(void* const* d_in, const int* in_sizes, int n_in,
                              void* d_out, int out_size, void* d_ws, size_t ws_size,
                              hipStream_t stream) {
    const float* g = (const float*)d_in[0];
    const float* caps = (const float*)d_in[1];
    const float* fc_w = (const float*)d_in[2];
    const float* fc_b = (const float*)d_in[3];

    float* out = (float*)d_out;
    float* x_out = out;                    // 38400
    float* xa_out = out + 38400;           // 2457600
    float* g_out = out + 38400 + 2457600;  // 7526400 floats = 30.1 MB scratch until final copy
    unsigned short* Abf = (unsigned short*)g_out;
    unsigned short* gT = Abf + (size_t)EMB * NCOLS;
    unsigned short* gbf = (unsigned short*)g_out;
    unsigned short* Hbf = gbf + (size_t)IMGS * EMB * KPAD;
    float* Ppart = g_out;

    float* ws = (float*)d_ws;
    float* hpool = ws;                                      // 38400 f
    int* idxs = (int*)(ws + 38400);                         // 11520
    float* vals = ws + 49920;                               // 11520
    float* H = ws + 61440;                                  // 200704 f
    unsigned short* Pbf = (unsigned short*)(ws + 262144);   // ends byte 5963776
    unsigned short* wbf = (unsigned short*)(ws + 1490944);  // ends byte 17483776
    bool use_wbf = ws_size >= (size_t)17483776;

    weldon_kernel<<<(IMGS * EMB) / 4, 256, 0, stream>>>(g, hpool);
    x_kernel<<<EMB, 64, 0, stream>>>(hpool, fc_w, fc_b, x_out);
    topk_kernel<<<CAPS, 256, 0, stream>>>(caps, idxs, vals);
    transpose_g_kernel<<<dim3(4, 25, IMGS), 256, 0, stream>>>(g, gT);

    if (use_wbf) {
        convert_w_kernel<<<(EMB * EMB / 4 + 255) / 256, 256, 0, stream>>>(fc_w, wbf);
        gemm_gll<5, 2, 0><<<dim3(NCOLS / 64, EMB / 160, 1), 256, 0, stream>>>(
            wbf, gT, Abf, EMB, NCOLS, EMB, EMB, 0, 0);
    } else {
        mfma_gemm_nt<5, 2, 0, float, unsigned short>
            <<<dim3(NCOLS / 64, EMB / 160), 256, 0, stream>>>(fc_w, gT, nullptr, Abf,
                                                              EMB, NCOLS, EMB, EMB);
    }
    heat_kernel<<<dim3((NCOLS / 4 + 255) / 256, CAPS), 256, 0, stream>>>(idxs, vals, Abf, H);
    norm_kernel<<<CAPS * IMGS, 64, 0, stream>>>(H, Hbf);
    convert_g_kernel<<<(IMGS * EMB) / 4, 256, 0, stream>>>(g, gbf);
    gemm_gll<2, 5, 3><<<dim3(EMB / 160, 1, IMGS), 256, 0, stream>>>(
        Hbf, gbf, Pbf, CAPS, EMB, KPAD, KPAD, (long)CAPS * KPAD, (long)EMB * KPAD);
    if (use_wbf) {
        gemm_gll<2, 5, 2><<<dim3(EMB / 160, (IMGS * CAPS) / 64, 3), 256, 0, stream>>>(
            Pbf, wbf, Ppart, IMGS * CAPS, EMB, EMB, 800, 0, 0);
    } else {
        mfma_gemm_nt<2, 3, 2, unsigned short, float>
            <<<dim3(EMB / 96, (IMGS * CAPS) / 64, 3), 256, 0, stream>>>(Pbf, fc_w, nullptr, Ppart,
                                                                        IMGS * CAPS, EMB, EMB, 800);
    }
    reduce3_kernel<<<(IMGS * CAPS * EMB / 4) / 256, 256, 0, stream>>>(Ppart, fc_b, xa_out);
    hipMemcpyAsync(g_out, g, sizeof(float) * (size_t)IMGS * EMB * HW,
                   hipMemcpyDeviceToDevice, stream);
}